// Round 3
// baseline (2835.120 us; speedup 1.0000x reference)
//
#include <hip/hip_runtime.h>
#include <hip/hip_bf16.h>
#include <math.h>

// Problem constants
#define BB 4
#define TT 2048
#define BT 8192          // B*T rows
#define DM 512           // d_model
#define DI 1024          // d_inner
#define NH 8
#define HD 128
#define DS 16
#define CONVD 1056       // DI + 2*DSTATE
#define DPROJ 2088       // 2*DI + 2*DSTATE + NHEADS
#define NL 4

typedef __hip_bfloat16 bf16;
typedef __attribute__((ext_vector_type(8))) short short8;
typedef __attribute__((ext_vector_type(4))) float f32x4;

static __device__ __forceinline__ float b2f_raw(short v){
  union { unsigned u; float f; } c; c.u = ((unsigned)(unsigned short)v) << 16; return c.f;
}

// block-wide reduce of two values across 256 threads (4 waves)
static __device__ __forceinline__ void red2(float& a, float& b, float* sb){
  #pragma unroll
  for (int o = 32; o; o >>= 1){ a += __shfl_down(a, o); b += __shfl_down(b, o); }
  int w = threadIdx.x >> 6;
  if ((threadIdx.x & 63) == 0){ sb[w] = a; sb[4+w] = b; }
  __syncthreads();
  a = sb[0]+sb[1]+sb[2]+sb[3];
  b = sb[4]+sb[5]+sb[6]+sb[7];
}

// ---------------------------------------------------------------------------
// Dtype sniffing: view x as bf16. True bf16 N(0,1) data -> ~0 "bad" values.
// fp32 data viewed as bf16 -> every 2nd halfword is random mantissa bits ->
// thousands of Inf/NaN/huge values. Writes flag: 1 = fp32 inputs, 0 = bf16.
// ---------------------------------------------------------------------------
__global__ __launch_bounds__(256) void detect_dtype(const void* x, int* flagp){
  __shared__ int cnt;
  if (threadIdx.x == 0) cnt = 0;
  __syncthreads();
  const bf16* p = (const bf16*)x;
  int bad = 0;
  for (int i = threadIdx.x; i < 32768; i += 256){
    float v = __bfloat162float(p[i]);
    if (!isfinite(v) || fabsf(v) > 1e4f) bad++;
  }
  atomicAdd(&cnt, bad);
  __syncthreads();
  if (threadIdx.x == 0) *flagp = (cnt > 100) ? 1 : 0;
}

// Canonicalize one input to bf16 per the detected dtype.
__global__ __launch_bounds__(256) void convert_in(const void* src, bf16* dst, int n,
                                                  const int* flagp){
  int f = *flagp;
  for (int i = blockIdx.x*256 + threadIdx.x; i < n; i += gridDim.x*256){
    if (f) dst[i] = __float2bfloat16(((const float*)src)[i]);
    else   dst[i] = ((const bf16*)src)[i];
  }
}

// ---------------------------------------------------------------------------
// Generic NT GEMM: C[z][M][N] = A[z][M][K(lda)] @ W_z[N][K]^T (bf16, fp32 acc)
// OP=0 plain, OP=1 +bias(X[N]), OP=2 +residual(X[z][M][N], may alias C!),
// OP=3 plain + fp32 side-store of cols >= DPROJ-8 (dt_raw) into aux[z][M][8].
// NOTE: C/X not __restrict__ — OP==2 does the residual add in place.
// ---------------------------------------------------------------------------
template<int OP>
__global__ __launch_bounds__(256) void gemm_nt(
    const bf16* __restrict__ A, const bf16* __restrict__ W0, const bf16* __restrict__ W1,
    bf16* C, const bf16* X, float* aux,
    int M, int N, int K, int lda, long sA, long sC)
{
  const int z = blockIdx.z;
  const bf16* Az = A + (long)z * sA;
  const bf16* W = z ? W1 : W0;
  const int m0 = blockIdx.x * 128, n0 = blockIdx.y * 128;
  __shared__ __align__(16) bf16 As[128*32];
  __shared__ __align__(16) bf16 Bs[128*32];
  const int tid  = threadIdx.x;
  const int lane = tid & 63, wv = tid >> 6;
  const int wm = wv >> 1, wn = wv & 1;          // wave -> 64x64 quadrant
  const int quad = lane >> 4, l16 = lane & 15;
  const int strow = tid >> 2;                   // staging row 0..63 (+64 on is=1)
  const int stbyt = (tid & 3) * 16;             // staging byte offset in 64B row

  f32x4 acc[4][4];
  #pragma unroll
  for (int i=0;i<4;i++)
    #pragma unroll
    for (int j=0;j<4;j++) acc[i][j] = (f32x4){0.f,0.f,0.f,0.f};

  for (int k0 = 0; k0 < K; k0 += 32){
    short8 va[2], vb[2];
    #pragma unroll
    for (int is = 0; is < 2; ++is){
      int r = is*64 + strow;                    // 0..127 tile row
      va[is] = *(const short8*)((const char*)(Az + (long)(m0 + r)*lda + k0) + stbyt);
      int rn = n0 + r; rn = rn < N ? rn : N-1;  // clamp OOB weight rows (cols >= N never stored)
      vb[is] = *(const short8*)((const char*)(W + (long)rn*K + k0) + stbyt);
    }
    __syncthreads();                            // prior iter's ds_reads complete
    #pragma unroll
    for (int is = 0; is < 2; ++is){
      int r = is*64 + strow;
      *(short8*)((char*)As + (long)r*64 + stbyt) = va[is];
      *(short8*)((char*)Bs + (long)r*64 + stbyt) = vb[is];
    }
    __syncthreads();
    short8 af[4], bfr[4];
    #pragma unroll
    for (int mi=0;mi<4;mi++) af[mi]  = *(const short8*)((const char*)As + (long)(wm*64+mi*16+l16)*64 + quad*16);
    #pragma unroll
    for (int ni=0;ni<4;ni++) bfr[ni] = *(const short8*)((const char*)Bs + (long)(wn*64+ni*16+l16)*64 + quad*16);
    #pragma unroll
    for (int mi=0;mi<4;mi++)
      #pragma unroll
      for (int ni=0;ni<4;ni++)
        acc[mi][ni] = __builtin_amdgcn_mfma_f32_16x16x32_bf16(af[mi], bfr[ni], acc[mi][ni], 0, 0, 0);
  }

  bf16* Cz = C + (long)z * sC;
  const bf16* Xz = (OP==2) ? (X + (long)z * sC) : X;
  #pragma unroll
  for (int mi=0;mi<4;mi++){
    #pragma unroll
    for (int ni=0;ni<4;ni++){
      #pragma unroll
      for (int r=0;r<4;r++){
        int row = m0 + wm*64 + mi*16 + quad*4 + r;
        int col = n0 + wn*64 + ni*16 + l16;
        if (col < N){
          float v = acc[mi][ni][r];
          if (OP==1) v += __bfloat162float(X[col]);
          if (OP==2) v += __bfloat162float(Xz[(long)row*N + col]);
          Cz[(long)row*N + col] = __float2bfloat16(v);
          if (OP==3 && col >= DPROJ-8)
            aux[(long)z*BT*8 + (long)row*8 + (col-(DPROJ-8))] = v;
        }
      }
    }
  }
}

// ---------------------------------------------------------------------------
// LayerNorm of embed output (512) -> h_f and time-reversed h_b
// ---------------------------------------------------------------------------
__global__ __launch_bounds__(256) void embed_ln(const bf16* __restrict__ hp,
    const bf16* __restrict__ w, const bf16* __restrict__ bb, bf16* __restrict__ h)
{
  __shared__ float sb[8];
  int bt = blockIdx.x; int b = bt >> 11, t = bt & 2047;
  const bf16* r = hp + (long)bt*DM;
  int c0 = threadIdx.x, c1 = threadIdx.x + 256;
  float v0 = __bfloat162float(r[c0]);
  float v1 = __bfloat162float(r[c1]);
  float s = v0+v1, ss = v0*v0+v1*v1;
  red2(s, ss, sb);
  float m = s / DM;
  float var = ss / DM - m*m;
  float rs = rsqrtf(fmaxf(var, 0.f) + 1e-5f);
  float a0 = (v0-m)*rs*__bfloat162float(w[c0]) + __bfloat162float(bb[c0]);
  float a1 = (v1-m)*rs*__bfloat162float(w[c1]) + __bfloat162float(bb[c1]);
  bf16* o0 = h + (long)bt*DM;
  bf16* o1 = h + ((long)BT + (long)b*TT + (TT-1-t)) * DM;
  o0[c0] = __float2bfloat16(a0); o0[c1] = __float2bfloat16(a1);
  o1[c0] = __float2bfloat16(a0); o1[c1] = __float2bfloat16(a1);
}

// ---------------------------------------------------------------------------
// Causal depthwise conv (K=4, cross-correlation per lax.conv) + bias + SiLU
// ---------------------------------------------------------------------------
__global__ __launch_bounds__(256) void conv_silu(const bf16* __restrict__ zx,
    const bf16* __restrict__ cw0, const bf16* __restrict__ cw1,
    const bf16* __restrict__ cb0, const bf16* __restrict__ cb1,
    bf16* __restrict__ xbc)
{
  int bt = blockIdx.x, dir = blockIdx.y;
  int t = bt & 2047;
  const bf16* cw = dir ? cw1 : cw0;
  const bf16* cb = dir ? cb1 : cb0;
  const bf16* zr = zx + ((long)dir*BT + bt)*DPROJ + DI;  // row t, col 1024
  bf16* orow = xbc + ((long)dir*BT + bt)*CONVD;
  for (int c = threadIdx.x; c < CONVD; c += 256){
    float acc = __bfloat162float(cb[c]);
    #pragma unroll
    for (int j=0;j<4;j++){
      int ts = t - 3 + j;
      if (ts >= 0)
        acc += __bfloat162float(cw[c*4+j]) * __bfloat162float(zr[(long)(j-3)*DPROJ + c]);
    }
    float sg = 1.f / (1.f + expf(-acc));
    orow[c] = __float2bfloat16(acc * sg);
  }
}

// ---------------------------------------------------------------------------
// dt = softplus(dt_raw + bias); dA = exp(-exp(A_log)*dt); packed as float2
// ---------------------------------------------------------------------------
__global__ __launch_bounds__(256) void dt_kernel(const float* __restrict__ draw,
    const bf16* __restrict__ db0, const bf16* __restrict__ db1,
    const bf16* __restrict__ al0, const bf16* __restrict__ al1,
    float2* __restrict__ dadt)
{
  int idx = blockIdx.x*256 + threadIdx.x;   // 2*8192*8 = 131072 total
  int dir = idx >> 16, r = idx & 65535;
  int bt = r >> 3, h = r & 7;
  int b = bt >> 11, t = bt & 2047;
  float x = draw[idx] + __bfloat162float((dir?db1:db0)[h]);
  float sp = (x > 20.f) ? x : log1pf(expf(x));
  float a = expf(-expf(__bfloat162float((dir?al1:al0)[h])) * sp);
  long o = (((long)dir*BB + b)*NH + h)*TT + t;
  float2 v; v.x = a; v.y = sp;
  dadt[o] = v;
}

// ---------------------------------------------------------------------------
// Sequential selective scan, IN-PLACE: y overwrites the x-region of xbc
// (stride CONVD). Safe: each x element is read only by the 2 lanes (p,half)
// of the wave that also writes it (wave-lockstep => load precedes store);
// B/C columns (>=1024) are never written; waves own disjoint p-columns.
// ---------------------------------------------------------------------------
#define SC_LOAD(X,BV,CV,DD,T0) do{ \
  _Pragma("unroll") \
  for (int _i=0;_i<4;_i++){ \
    const bf16* _rr = xr + (long)((T0)+_i)*CONVD; \
    X[_i]  = __bfloat162float(_rr[h*HD + p]); \
    BV[_i] = *(const short8*)(_rr + DI + half*8); \
    CV[_i] = *(const short8*)(_rr + DI + DS + half*8); \
    DD[_i] = ddr[(T0)+_i]; \
  } }while(0)

#define SC_STEP(X,BV,CV,DD,T0) do{ \
  _Pragma("unroll") \
  for (int _i=0;_i<4;_i++){ \
    float _dav = DD[_i].x, _dtv = DD[_i].y; \
    float _xdt = X[_i] * _dtv; \
    float _acc = 0.f; \
    _Pragma("unroll") \
    for (int _n=0;_n<8;_n++){ \
      s[_n] = fmaf(_dav, s[_n], _xdt * b2f_raw(BV[_i][_n])); \
      _acc  = fmaf(s[_n], b2f_raw(CV[_i][_n]), _acc); } \
    _acc += __shfl_xor(_acc, 1); \
    if (!half) xw[(long)((T0)+_i)*CONVD + h*HD + p] = __float2bfloat16(_acc + Dv*X[_i]); \
  } }while(0)

__global__ __launch_bounds__(256) void scan_seq(bf16* __restrict__ xbc,
    const float2* __restrict__ dadt,
    const bf16* __restrict__ D0, const bf16* __restrict__ D1)
{
  int bid = blockIdx.x;
  int dir = bid >> 5, b = (bid >> 3) & 3, h = bid & 7;
  int tid = threadIdx.x, p = tid >> 1, half = tid & 1;
  const bf16* xr = xbc + ((long)dir*BT + (long)b*TT) * CONVD;
  bf16* xw = xbc + ((long)dir*BT + (long)b*TT) * CONVD;
  const float2* ddr = dadt + (((long)dir*BB + b)*NH + h)*TT;
  float Dv = __bfloat162float(dir ? D1[h] : D0[h]);
  float s[8];
  #pragma unroll
  for (int n=0;n<8;n++) s[n] = 0.f;

  float xA[4], xB2[4];
  short8 BA[4], BB2[4], CA[4], CB2[4];
  float2 dA_[4], dB_[4];

  SC_LOAD(xA,BA,CA,dA_, 0);
  for (int t0 = 0; t0 < TT; t0 += 8){
    if (t0+4 < TT) SC_LOAD(xB2,BB2,CB2,dB_, t0+4);
    SC_STEP(xA,BA,CA,dA_, t0);
    if (t0+8 < TT) SC_LOAD(xA,BA,CA,dA_, t0+8);
    SC_STEP(xB2,BB2,CB2,dB_, t0+4);
  }
}

// ---------------------------------------------------------------------------
// g = y*silu(z); g *= rsqrt(mean(g^2)+eps)*rms_w.  y read from xbc (stride
// CONVD); g written IN-PLACE into the z-columns (0..1023) of zx. Each thread
// reads and writes only its own columns -> no cross-thread hazard.
// ---------------------------------------------------------------------------
__global__ __launch_bounds__(256) void gate_rms(const bf16* __restrict__ xbc, bf16* zx,
    const bf16* __restrict__ rw0, const bf16* __restrict__ rw1)
{
  __shared__ float sb[8];
  int bt = blockIdx.x, dir = blockIdx.y;
  const bf16* yr = xbc + ((long)dir*BT + bt)*CONVD;
  bf16* zr = zx + ((long)dir*BT + bt)*DPROJ;
  const bf16* rw = dir ? rw1 : rw0;
  float gv[4], ss = 0.f, dummy = 0.f;
  #pragma unroll
  for (int i=0;i<4;i++){
    int c = threadIdx.x + i*256;
    float yv = __bfloat162float(yr[c]);
    float zv = __bfloat162float(zr[c]);
    float sg = 1.f/(1.f+expf(-zv));
    gv[i] = yv * zv * sg;
    ss += gv[i]*gv[i];
  }
  red2(ss, dummy, sb);
  float sc = rsqrtf(ss / DI + 1e-5f);
  #pragma unroll
  for (int i=0;i<4;i++){
    int c = threadIdx.x + i*256;
    zr[c] = __float2bfloat16(gv[i]*sc*__bfloat162float(rw[c]));
  }
}

// ---------------------------------------------------------------------------
// Final LN over concat(h_f[b,t], h_b[b,T-1-t]) (1024) -> d_out.
// mode&flag select bf16 vs fp32 output store.
// ---------------------------------------------------------------------------
__global__ __launch_bounds__(256) void final_ln(const bf16* __restrict__ h,
    const bf16* __restrict__ lw, const bf16* __restrict__ lb, void* out,
    int mode, const int* flagp)
{
  __shared__ float sb[8];
  int bt = blockIdx.x; int b = bt >> 11, t = bt & 2047;
  int f32out = mode ? *flagp : 0;
  const bf16* rf = h + (long)bt*DM;
  const bf16* rb = h + ((long)BT + (long)b*TT + (TT-1-t))*DM;
  float v[4], s = 0.f, ss = 0.f;
  #pragma unroll
  for (int i=0;i<4;i++){
    int c = threadIdx.x + i*256;
    v[i] = __bfloat162float(c < DM ? rf[c] : rb[c-DM]);
    s += v[i]; ss += v[i]*v[i];
  }
  red2(s, ss, sb);
  float m = s / (2*DM);
  float var = ss / (2*DM) - m*m;
  float rs = rsqrtf(fmaxf(var, 0.f) + 1e-5f);
  #pragma unroll
  for (int i=0;i<4;i++){
    int c = threadIdx.x + i*256;
    float o = (v[i]-m)*rs*__bfloat162float(lw[c]) + __bfloat162float(lb[c]);
    if (f32out) ((float*)out)[(long)bt*(2*DM) + c] = o;
    else        ((bf16*)out)[(long)bt*(2*DM) + c] = __float2bfloat16(o);
  }
}

// ---------------------------------------------------------------------------
extern "C" void kernel_launch(void* const* d_in, const int* in_sizes, int n_in,
                              void* d_out, int out_size, void* d_ws, size_t ws_size,
                              hipStream_t stream)
{
  // Workspace layout (64B-aligned chunks)
  char* wsp = (char*)d_ws;
  auto take = [&](size_t bytes){ char* p = wsp; wsp += (bytes + 63) & ~(size_t)63; return p; };
  int*   flagp = (int*)  take(4);
  bf16*  h     = (bf16*) take((size_t)2*BT*DM*2);      // 16.78 MB
  bf16*  zx    = (bf16*) take((size_t)2*BT*DPROJ*2);   // 68.42 MB (z gated in place)
  bf16*  xbc   = (bf16*) take((size_t)2*BT*CONVD*2);   // 34.60 MB (y scanned in place)
  float2* dadt = (float2*)take((size_t)2*BB*NH*TT*8);  // 1.05 MB
  float* draw  = (float*)take((size_t)2*BT*NH*4);      // 0.52 MB
  size_t needDirect = (size_t)(wsp - (char*)d_ws);     // ~121.4 MB

  // canonical bf16 input copies (element counts per setup_inputs)
  static const int cnt[23] = {
    BT*256, DM*256, DM, DM, DM, 2*DM, 2*DM,
    NL*DPROJ*DM, NL*CONVD*4, NL*CONVD, NL*NH, NL*NH, NL*NH, NL*DI, NL*DM*DI,
    NL*DPROJ*DM, NL*CONVD*4, NL*CONVD, NL*NH, NL*NH, NL*NH, NL*DI, NL*DM*DI };
  bf16* canon[23];
  for (int i = 0; i < 23; ++i) canon[i] = (bf16*)take((size_t)cnt[i]*2);
  size_t needFull = (size_t)(wsp - (char*)d_ws);       // ~159.5 MB

  const int convMode = (ws_size >= needFull) ? 1 : 0;

  const bf16* in[23];
  if (convMode){
    detect_dtype<<<1,256,0,stream>>>(d_in[0], flagp);
    for (int i = 0; i < 23; ++i){
      int grid = (cnt[i] + 255)/256; if (grid > 2048) grid = 2048;
      convert_in<<<grid,256,0,stream>>>(d_in[i], canon[i], cnt[i], flagp);
      in[i] = canon[i];
    }
  } else {
    for (int i = 0; i < 23; ++i) in[i] = (const bf16*)d_in[i];
  }

  const bf16* x       = in[0];
  const bf16* embed_w = in[1];
  const bf16* embed_b = in[2];
  const bf16* ln1_w   = in[3];
  const bf16* ln1_b   = in[4];
  const bf16* lnout_w = in[5];
  const bf16* lnout_b = in[6];
  const bf16* in_w[2]   = {in[7],  in[15]};
  const bf16* conv_w[2] = {in[8],  in[16]};
  const bf16* conv_b[2] = {in[9],  in[17]};
  const bf16* dt_b[2]   = {in[10], in[18]};
  const bf16* A_log[2]  = {in[11], in[19]};
  const bf16* Dp[2]     = {in[12], in[20]};
  const bf16* rms_w[2]  = {in[13], in[21]};
  const bf16* out_w[2]  = {in[14], in[22]};

  bf16* hpre = xbc;   // embed output parks in xbc (free until layer-0 conv)

  // embed GEMM (+bias), then LN -> h_f and reversed h_b
  gemm_nt<1><<<dim3(64,4,1),256,0,stream>>>(x, embed_w, embed_w, hpre, embed_b, nullptr,
                                            BT, DM, 256, 256, 0, 0);
  embed_ln<<<dim3(BT),256,0,stream>>>(hpre, ln1_w, ln1_b, h);

  for (int i = 0; i < NL; ++i){
    gemm_nt<3><<<dim3(64,17,2),256,0,stream>>>(h, in_w[0]+(size_t)i*DPROJ*DM, in_w[1]+(size_t)i*DPROJ*DM,
        zx, nullptr, draw, BT, DPROJ, DM, DM, (long)BT*DM, (long)BT*DPROJ);
    conv_silu<<<dim3(BT,2),256,0,stream>>>(zx, conv_w[0]+(size_t)i*CONVD*4, conv_w[1]+(size_t)i*CONVD*4,
        conv_b[0]+(size_t)i*CONVD, conv_b[1]+(size_t)i*CONVD, xbc);
    dt_kernel<<<dim3(512),256,0,stream>>>(draw, dt_b[0]+i*NH, dt_b[1]+i*NH,
        A_log[0]+i*NH, A_log[1]+i*NH, dadt);
    scan_seq<<<dim3(64),256,0,stream>>>(xbc, dadt, Dp[0]+i*NH, Dp[1]+i*NH);
    gate_rms<<<dim3(BT,2),256,0,stream>>>(xbc, zx, rms_w[0]+(size_t)i*DI, rms_w[1]+(size_t)i*DI);
    gemm_nt<2><<<dim3(64,4,2),256,0,stream>>>(zx, out_w[0]+(size_t)i*DM*DI, out_w[1]+(size_t)i*DM*DI,
        h, h, nullptr, BT, DM, DI, DPROJ, (long)BT*DPROJ, (long)BT*DM);
  }

  final_ln<<<dim3(BT),256,0,stream>>>(h, lnout_w, lnout_b, d_out, convMode, flagp);
  (void)needDirect; (void)in_sizes; (void)n_in; (void)out_size; (void)ws_size;
}

// Round 4
// 1366.754 us; speedup vs baseline: 2.0743x; 2.0743x over previous
//
#include <hip/hip_runtime.h>
#include <hip/hip_bf16.h>
#include <math.h>

// Problem constants
#define BB 4
#define TT 2048
#define BT 8192          // B*T rows
#define DM 512           // d_model
#define DI 1024          // d_inner
#define NH 8
#define HD 128
#define DS 16
#define CONVD 1056       // DI + 2*DSTATE
#define DPROJ 2088       // 2*DI + 2*DSTATE + NHEADS
#define NL 4
#define CL 128           // scan chunk length
#define NCH 16           // TT / CL
#define NE 131072        // 64 dirbh * 2048 state elems

typedef __hip_bfloat16 bf16;
typedef __attribute__((ext_vector_type(8))) short short8;
typedef __attribute__((ext_vector_type(4))) float f32x4;

static __device__ __forceinline__ float b2f_raw(short v){
  union { unsigned u; float f; } c; c.u = ((unsigned)(unsigned short)v) << 16; return c.f;
}

// block-wide reduce of two values across 256 threads (4 waves)
static __device__ __forceinline__ void red2(float& a, float& b, float* sb){
  #pragma unroll
  for (int o = 32; o; o >>= 1){ a += __shfl_down(a, o); b += __shfl_down(b, o); }
  int w = threadIdx.x >> 6;
  if ((threadIdx.x & 63) == 0){ sb[w] = a; sb[4+w] = b; }
  __syncthreads();
  a = sb[0]+sb[1]+sb[2]+sb[3];
  b = sb[4]+sb[5]+sb[6]+sb[7];
}

// ---------------------------------------------------------------------------
// Dtype sniffing (proven-safe round 3; kept unchanged).
// ---------------------------------------------------------------------------
__global__ __launch_bounds__(256) void detect_dtype(const void* x, int* flagp){
  __shared__ int cnt;
  if (threadIdx.x == 0) cnt = 0;
  __syncthreads();
  const bf16* p = (const bf16*)x;
  int bad = 0;
  for (int i = threadIdx.x; i < 32768; i += 256){
    float v = __bfloat162float(p[i]);
    if (!isfinite(v) || fabsf(v) > 1e4f) bad++;
  }
  atomicAdd(&cnt, bad);
  __syncthreads();
  if (threadIdx.x == 0) *flagp = (cnt > 100) ? 1 : 0;
}

__global__ __launch_bounds__(256) void convert_in(const void* src, bf16* dst, int n,
                                                  const int* flagp){
  int f = *flagp;
  for (int i = blockIdx.x*256 + threadIdx.x; i < n; i += gridDim.x*256){
    if (f) dst[i] = __float2bfloat16(((const float*)src)[i]);
    else   dst[i] = ((const bf16*)src)[i];
  }
}

// ---------------------------------------------------------------------------
// Generic NT GEMM: C[z][M][N] = A[z][M][K(lda)] @ W_z[N][K]^T (bf16, fp32 acc)
// OP=0 plain, OP=1 +bias(X[N]), OP=2 +residual(X[z][M][N], may alias C!),
// OP=3 plain + fp32 side-store of cols >= DPROJ-8 (dt_raw) into aux[z][M][8].
// ---------------------------------------------------------------------------
template<int OP>
__global__ __launch_bounds__(256) void gemm_nt(
    const bf16* __restrict__ A, const bf16* __restrict__ W0, const bf16* __restrict__ W1,
    bf16* C, const bf16* X, float* aux,
    int M, int N, int K, int lda, long sA, long sC)
{
  const int z = blockIdx.z;
  const bf16* Az = A + (long)z * sA;
  const bf16* W = z ? W1 : W0;
  const int m0 = blockIdx.x * 128, n0 = blockIdx.y * 128;
  __shared__ __align__(16) bf16 As[128*32];
  __shared__ __align__(16) bf16 Bs[128*32];
  const int tid  = threadIdx.x;
  const int lane = tid & 63, wv = tid >> 6;
  const int wm = wv >> 1, wn = wv & 1;          // wave -> 64x64 quadrant
  const int quad = lane >> 4, l16 = lane & 15;
  const int strow = tid >> 2;                   // staging row 0..63 (+64 on is=1)
  const int stbyt = (tid & 3) * 16;             // staging byte offset in 64B row

  f32x4 acc[4][4];
  #pragma unroll
  for (int i=0;i<4;i++)
    #pragma unroll
    for (int j=0;j<4;j++) acc[i][j] = (f32x4){0.f,0.f,0.f,0.f};

  for (int k0 = 0; k0 < K; k0 += 32){
    short8 va[2], vb[2];
    #pragma unroll
    for (int is = 0; is < 2; ++is){
      int r = is*64 + strow;                    // 0..127 tile row
      va[is] = *(const short8*)((const char*)(Az + (long)(m0 + r)*lda + k0) + stbyt);
      int rn = n0 + r; rn = rn < N ? rn : N-1;  // clamp OOB weight rows (cols >= N never stored)
      vb[is] = *(const short8*)((const char*)(W + (long)rn*K + k0) + stbyt);
    }
    __syncthreads();                            // prior iter's ds_reads complete
    #pragma unroll
    for (int is = 0; is < 2; ++is){
      int r = is*64 + strow;
      *(short8*)((char*)As + (long)r*64 + stbyt) = va[is];
      *(short8*)((char*)Bs + (long)r*64 + stbyt) = vb[is];
    }
    __syncthreads();
    short8 af[4], bfr[4];
    #pragma unroll
    for (int mi=0;mi<4;mi++) af[mi]  = *(const short8*)((const char*)As + (long)(wm*64+mi*16+l16)*64 + quad*16);
    #pragma unroll
    for (int ni=0;ni<4;ni++) bfr[ni] = *(const short8*)((const char*)Bs + (long)(wn*64+ni*16+l16)*64 + quad*16);
    #pragma unroll
    for (int mi=0;mi<4;mi++)
      #pragma unroll
      for (int ni=0;ni<4;ni++)
        acc[mi][ni] = __builtin_amdgcn_mfma_f32_16x16x32_bf16(af[mi], bfr[ni], acc[mi][ni], 0, 0, 0);
  }

  bf16* Cz = C + (long)z * sC;
  const bf16* Xz = (OP==2) ? (X + (long)z * sC) : X;
  #pragma unroll
  for (int mi=0;mi<4;mi++){
    #pragma unroll
    for (int ni=0;ni<4;ni++){
      #pragma unroll
      for (int r=0;r<4;r++){
        int row = m0 + wm*64 + mi*16 + quad*4 + r;
        int col = n0 + wn*64 + ni*16 + l16;
        if (col < N){
          float v = acc[mi][ni][r];
          if (OP==1) v += __bfloat162float(X[col]);
          if (OP==2) v += __bfloat162float(Xz[(long)row*N + col]);
          Cz[(long)row*N + col] = __float2bfloat16(v);
          if (OP==3 && col >= DPROJ-8)
            aux[(long)z*BT*8 + (long)row*8 + (col-(DPROJ-8))] = v;
        }
      }
    }
  }
}

// ---------------------------------------------------------------------------
// LayerNorm of embed output (512) -> h_f and time-reversed h_b
// ---------------------------------------------------------------------------
__global__ __launch_bounds__(256) void embed_ln(const bf16* __restrict__ hp,
    const bf16* __restrict__ w, const bf16* __restrict__ bb, bf16* __restrict__ h)
{
  __shared__ float sb[8];
  int bt = blockIdx.x; int b = bt >> 11, t = bt & 2047;
  const bf16* r = hp + (long)bt*DM;
  int c0 = threadIdx.x, c1 = threadIdx.x + 256;
  float v0 = __bfloat162float(r[c0]);
  float v1 = __bfloat162float(r[c1]);
  float s = v0+v1, ss = v0*v0+v1*v1;
  red2(s, ss, sb);
  float m = s / DM;
  float var = ss / DM - m*m;
  float rs = rsqrtf(fmaxf(var, 0.f) + 1e-5f);
  float a0 = (v0-m)*rs*__bfloat162float(w[c0]) + __bfloat162float(bb[c0]);
  float a1 = (v1-m)*rs*__bfloat162float(w[c1]) + __bfloat162float(bb[c1]);
  bf16* o0 = h + (long)bt*DM;
  bf16* o1 = h + ((long)BT + (long)b*TT + (TT-1-t)) * DM;
  o0[c0] = __float2bfloat16(a0); o0[c1] = __float2bfloat16(a1);
  o1[c0] = __float2bfloat16(a0); o1[c1] = __float2bfloat16(a1);
}

// ---------------------------------------------------------------------------
// Causal depthwise conv (K=4) + bias + SiLU
// ---------------------------------------------------------------------------
__global__ __launch_bounds__(256) void conv_silu(const bf16* __restrict__ zx,
    const bf16* __restrict__ cw0, const bf16* __restrict__ cw1,
    const bf16* __restrict__ cb0, const bf16* __restrict__ cb1,
    bf16* __restrict__ xbc)
{
  int bt = blockIdx.x, dir = blockIdx.y;
  int t = bt & 2047;
  const bf16* cw = dir ? cw1 : cw0;
  const bf16* cb = dir ? cb1 : cb0;
  const bf16* zr = zx + ((long)dir*BT + bt)*DPROJ + DI;  // row t, col 1024
  bf16* orow = xbc + ((long)dir*BT + bt)*CONVD;
  for (int c = threadIdx.x; c < CONVD; c += 256){
    float acc = __bfloat162float(cb[c]);
    #pragma unroll
    for (int j=0;j<4;j++){
      int ts = t - 3 + j;
      if (ts >= 0)
        acc += __bfloat162float(cw[c*4+j]) * __bfloat162float(zr[(long)(j-3)*DPROJ + c]);
    }
    float sg = 1.f / (1.f + expf(-acc));
    orow[c] = __float2bfloat16(acc * sg);
  }
}

// ---------------------------------------------------------------------------
// dt = softplus(dt_raw + bias); dA = exp(-exp(A_log)*dt); packed as float2
// ---------------------------------------------------------------------------
__global__ __launch_bounds__(256) void dt_kernel(const float* __restrict__ draw,
    const bf16* __restrict__ db0, const bf16* __restrict__ db1,
    const bf16* __restrict__ al0, const bf16* __restrict__ al1,
    float2* __restrict__ dadt)
{
  int idx = blockIdx.x*256 + threadIdx.x;   // 2*8192*8 = 131072 total
  int dir = idx >> 16, r = idx & 65535;
  int bt = r >> 3, h = r & 7;
  int b = bt >> 11, t = bt & 2047;
  float x = draw[idx] + __bfloat162float((dir?db1:db0)[h]);
  float sp = (x > 20.f) ? x : log1pf(expf(x));
  float a = expf(-expf(__bfloat162float((dir?al1:al0)[h])) * sp);
  long o = (((long)dir*BB + b)*NH + h)*TT + t;
  float2 v; v.x = a; v.y = sp;
  dadt[o] = v;
}

// ---------------------------------------------------------------------------
// Chunked selective scan (SSD): the transition is SCALAR per (b,h,t), so
// chunk recombination is exact:  s_t = P(c0..t)*S_init_c + s_t^local.
// Pass 1: per-chunk local scan from 0 -> SC[c][e], chunk dA-product Pc.
// Pass 2: 16-step exclusive scan over chunks, in place (SC becomes S_init).
// Pass 3: rescan chunk seeded with S_init, write y in place into xbc.
// ---------------------------------------------------------------------------
#define SC_LOAD(X,BV,CV,DD,T0) do{ \
  _Pragma("unroll") \
  for (int _i=0;_i<4;_i++){ \
    const bf16* _rr = xr + (long)((T0)+_i)*CONVD; \
    X[_i]  = __bfloat162float(_rr[h*HD + p]); \
    BV[_i] = *(const short8*)(_rr + DI + half*8); \
    CV[_i] = *(const short8*)(_rr + DI + DS + half*8); \
    DD[_i] = ddr[(T0)+_i]; \
  } }while(0)

#define SC_STEP(X,BV,CV,DD,T0) do{ \
  _Pragma("unroll") \
  for (int _i=0;_i<4;_i++){ \
    float _dav = DD[_i].x, _dtv = DD[_i].y; \
    float _xdt = X[_i] * _dtv; \
    float _acc = 0.f; \
    _Pragma("unroll") \
    for (int _n=0;_n<8;_n++){ \
      s[_n] = fmaf(_dav, s[_n], _xdt * b2f_raw(BV[_i][_n])); \
      _acc  = fmaf(s[_n], b2f_raw(CV[_i][_n]), _acc); } \
    _acc += __shfl_xor(_acc, 1); \
    if (!half) xw[(long)((T0)+_i)*CONVD + h*HD + p] = __float2bfloat16(_acc + Dv*X[_i]); \
  } }while(0)

#define CH_LOAD(X,BV,DD,T0) do{ \
  _Pragma("unroll") \
  for (int _i=0;_i<4;_i++){ \
    const bf16* _rr = xr + (long)((T0)+_i)*CONVD; \
    X[_i]  = __bfloat162float(_rr[h*HD + p]); \
    BV[_i] = *(const short8*)(_rr + DI + half*8); \
    DD[_i] = ddr[(T0)+_i]; \
  } }while(0)

#define CH_STEP(X,BV,DD) do{ \
  _Pragma("unroll") \
  for (int _i=0;_i<4;_i++){ \
    float _dav = DD[_i].x, _dtv = DD[_i].y; \
    float _xdt = X[_i] * _dtv; \
    _Pragma("unroll") \
    for (int _n=0;_n<8;_n++) \
      s[_n] = fmaf(_dav, s[_n], _xdt * b2f_raw(BV[_i][_n])); \
    pacc *= _dav; \
  } }while(0)

__global__ __launch_bounds__(256) void chunk_local(const bf16* __restrict__ xbc,
    const float2* __restrict__ dadt, float* __restrict__ SC, float* __restrict__ Pc)
{
  int c = blockIdx.x, dbh = blockIdx.y;
  int dir = dbh >> 5, b = (dbh >> 3) & 3, h = dbh & 7;
  int tid = threadIdx.x, p = tid >> 1, half = tid & 1;
  const bf16* xr = xbc + ((long)dir*BT + (long)b*TT) * CONVD;
  const float2* ddr = dadt + (((long)dir*BB + b)*NH + h)*TT;
  float s[8];
  #pragma unroll
  for (int n=0;n<8;n++) s[n] = 0.f;
  float pacc = 1.f;
  const int c0 = c*CL;

  float xA[4], xB2[4];
  short8 BA[4], BB2[4];
  float2 dA_[4], dB_[4];

  CH_LOAD(xA,BA,dA_, c0);
  for (int t0 = c0; t0 < c0+CL; t0 += 8){
    CH_LOAD(xB2,BB2,dB_, t0+4);
    CH_STEP(xA,BA,dA_);
    if (t0+8 < c0+CL) CH_LOAD(xA,BA,dA_, t0+8);
    CH_STEP(xB2,BB2,dB_);
  }
  long e = (long)dbh*2048 + p*16 + half*8;
  #pragma unroll
  for (int n=0;n<8;n++) SC[(long)c*NE + e + n] = s[n];
  if (tid == 0) Pc[dbh*NCH + c] = pacc;
}

__global__ __launch_bounds__(256) void chunk_combine(float* __restrict__ SC,
    const float* __restrict__ Pc)
{
  int e = blockIdx.x*256 + threadIdx.x;   // 131072 total
  int dbh = e >> 11;
  float s = 0.f;
  #pragma unroll
  for (int c=0;c<NCH;c++){
    float tmp = SC[(long)c*NE + e];
    SC[(long)c*NE + e] = s;               // exclusive scan in place -> S_init
    s = Pc[dbh*NCH + c]*s + tmp;
  }
}

__global__ __launch_bounds__(256) void chunk_apply(bf16* __restrict__ xbc,
    const float2* __restrict__ dadt, const float* __restrict__ SC,
    const bf16* __restrict__ D0, const bf16* __restrict__ D1)
{
  int c = blockIdx.x, dbh = blockIdx.y;
  int dir = dbh >> 5, b = (dbh >> 3) & 3, h = dbh & 7;
  int tid = threadIdx.x, p = tid >> 1, half = tid & 1;
  const bf16* xr = xbc + ((long)dir*BT + (long)b*TT) * CONVD;
  bf16* xw = xbc + ((long)dir*BT + (long)b*TT) * CONVD;
  const float2* ddr = dadt + (((long)dir*BB + b)*NH + h)*TT;
  float Dv = __bfloat162float(dir ? D1[h] : D0[h]);
  long e = (long)dbh*2048 + p*16 + half*8;
  float s[8];
  #pragma unroll
  for (int n=0;n<8;n++) s[n] = SC[(long)c*NE + e + n];
  const int c0 = c*CL;

  float xA[4], xB2[4];
  short8 BA[4], BB2[4], CA[4], CB2[4];
  float2 dA_[4], dB_[4];

  SC_LOAD(xA,BA,CA,dA_, c0);
  for (int t0 = c0; t0 < c0+CL; t0 += 8){
    SC_LOAD(xB2,BB2,CB2,dB_, t0+4);
    SC_STEP(xA,BA,CA,dA_, t0);
    if (t0+8 < c0+CL) SC_LOAD(xA,BA,CA,dA_, t0+8);
    SC_STEP(xB2,BB2,CB2,dB_, t0+4);
  }
}

// ---------------------------------------------------------------------------
// g = y*silu(z), gated RMSNorm; in place into z-columns of zx
// ---------------------------------------------------------------------------
__global__ __launch_bounds__(256) void gate_rms(const bf16* __restrict__ xbc, bf16* zx,
    const bf16* __restrict__ rw0, const bf16* __restrict__ rw1)
{
  __shared__ float sb[8];
  int bt = blockIdx.x, dir = blockIdx.y;
  const bf16* yr = xbc + ((long)dir*BT + bt)*CONVD;
  bf16* zr = zx + ((long)dir*BT + bt)*DPROJ;
  const bf16* rw = dir ? rw1 : rw0;
  float gv[4], ss = 0.f, dummy = 0.f;
  #pragma unroll
  for (int i=0;i<4;i++){
    int c = threadIdx.x + i*256;
    float yv = __bfloat162float(yr[c]);
    float zv = __bfloat162float(zr[c]);
    float sg = 1.f/(1.f+expf(-zv));
    gv[i] = yv * zv * sg;
    ss += gv[i]*gv[i];
  }
  red2(ss, dummy, sb);
  float sc = rsqrtf(ss / DI + 1e-5f);
  #pragma unroll
  for (int i=0;i<4;i++){
    int c = threadIdx.x + i*256;
    zr[c] = __float2bfloat16(gv[i]*sc*__bfloat162float(rw[c]));
  }
}

// ---------------------------------------------------------------------------
// Final LN over concat(h_f[b,t], h_b[b,T-1-t]) (1024) -> d_out
// ---------------------------------------------------------------------------
__global__ __launch_bounds__(256) void final_ln(const bf16* __restrict__ h,
    const bf16* __restrict__ lw, const bf16* __restrict__ lb, void* out,
    int mode, const int* flagp)
{
  __shared__ float sb[8];
  int bt = blockIdx.x; int b = bt >> 11, t = bt & 2047;
  int f32out = mode ? *flagp : 0;
  const bf16* rf = h + (long)bt*DM;
  const bf16* rb = h + ((long)BT + (long)b*TT + (TT-1-t))*DM;
  float v[4], s = 0.f, ss = 0.f;
  #pragma unroll
  for (int i=0;i<4;i++){
    int c = threadIdx.x + i*256;
    v[i] = __bfloat162float(c < DM ? rf[c] : rb[c-DM]);
    s += v[i]; ss += v[i]*v[i];
  }
  red2(s, ss, sb);
  float m = s / (2*DM);
  float var = ss / (2*DM) - m*m;
  float rs = rsqrtf(fmaxf(var, 0.f) + 1e-5f);
  #pragma unroll
  for (int i=0;i<4;i++){
    int c = threadIdx.x + i*256;
    float o = (v[i]-m)*rs*__bfloat162float(lw[c]) + __bfloat162float(lb[c]);
    if (f32out) ((float*)out)[(long)bt*(2*DM) + c] = o;
    else        ((bf16*)out)[(long)bt*(2*DM) + c] = __float2bfloat16(o);
  }
}

// ---------------------------------------------------------------------------
extern "C" void kernel_launch(void* const* d_in, const int* in_sizes, int n_in,
                              void* d_out, int out_size, void* d_ws, size_t ws_size,
                              hipStream_t stream)
{
  char* wsp = (char*)d_ws;
  auto take = [&](size_t bytes){ char* p = wsp; wsp += (bytes + 63) & ~(size_t)63; return p; };
  int*   flagp = (int*)  take(4);
  bf16*  h     = (bf16*) take((size_t)2*BT*DM*2);      // 16.78 MB
  bf16*  zx    = (bf16*) take((size_t)2*BT*DPROJ*2);   // 68.42 MB (z gated in place)
  bf16*  xbc   = (bf16*) take((size_t)2*BT*CONVD*2);   // 34.60 MB (y scanned in place)
  float2* dadt = (float2*)take((size_t)2*BB*NH*TT*8);  // 1.05 MB
  float* draw  = (float*)take((size_t)2*BT*NH*4);      // 0.52 MB
  float* Pc    = (float*)take((size_t)64*NCH*4);       // 4 KB
  float* SC    = (float*)take((size_t)NCH*NE*4);       // 8.39 MB chunk states
  size_t needDirect = (size_t)(wsp - (char*)d_ws);     // ~129.8 MB

  static const int cnt[23] = {
    BT*256, DM*256, DM, DM, DM, 2*DM, 2*DM,
    NL*DPROJ*DM, NL*CONVD*4, NL*CONVD, NL*NH, NL*NH, NL*NH, NL*DI, NL*DM*DI,
    NL*DPROJ*DM, NL*CONVD*4, NL*CONVD, NL*NH, NL*NH, NL*NH, NL*DI, NL*DM*DI };
  bf16* canon[23];
  for (int i = 0; i < 23; ++i) canon[i] = (bf16*)take((size_t)cnt[i]*2);
  size_t needFull = (size_t)(wsp - (char*)d_ws);       // ~167.9 MB

  const int convMode = (ws_size >= needFull) ? 1 : 0;

  const bf16* in[23];
  if (convMode){
    detect_dtype<<<1,256,0,stream>>>(d_in[0], flagp);
    for (int i = 0; i < 23; ++i){
      int grid = (cnt[i] + 255)/256; if (grid > 2048) grid = 2048;
      convert_in<<<grid,256,0,stream>>>(d_in[i], canon[i], cnt[i], flagp);
      in[i] = canon[i];
    }
  } else {
    for (int i = 0; i < 23; ++i) in[i] = (const bf16*)d_in[i];
  }

  const bf16* x       = in[0];
  const bf16* embed_w = in[1];
  const bf16* embed_b = in[2];
  const bf16* ln1_w   = in[3];
  const bf16* ln1_b   = in[4];
  const bf16* lnout_w = in[5];
  const bf16* lnout_b = in[6];
  const bf16* in_w[2]   = {in[7],  in[15]};
  const bf16* conv_w[2] = {in[8],  in[16]};
  const bf16* conv_b[2] = {in[9],  in[17]};
  const bf16* dt_b[2]   = {in[10], in[18]};
  const bf16* A_log[2]  = {in[11], in[19]};
  const bf16* Dp[2]     = {in[12], in[20]};
  const bf16* rms_w[2]  = {in[13], in[21]};
  const bf16* out_w[2]  = {in[14], in[22]};

  bf16* hpre = xbc;   // embed output parks in xbc (free until layer-0 conv)

  gemm_nt<1><<<dim3(64,4,1),256,0,stream>>>(x, embed_w, embed_w, hpre, embed_b, nullptr,
                                            BT, DM, 256, 256, 0, 0);
  embed_ln<<<dim3(BT),256,0,stream>>>(hpre, ln1_w, ln1_b, h);

  for (int i = 0; i < NL; ++i){
    gemm_nt<3><<<dim3(64,17,2),256,0,stream>>>(h, in_w[0]+(size_t)i*DPROJ*DM, in_w[1]+(size_t)i*DPROJ*DM,
        zx, nullptr, draw, BT, DPROJ, DM, DM, (long)BT*DM, (long)BT*DPROJ);
    conv_silu<<<dim3(BT,2),256,0,stream>>>(zx, conv_w[0]+(size_t)i*CONVD*4, conv_w[1]+(size_t)i*CONVD*4,
        conv_b[0]+(size_t)i*CONVD, conv_b[1]+(size_t)i*CONVD, xbc);
    dt_kernel<<<dim3(512),256,0,stream>>>(draw, dt_b[0]+i*NH, dt_b[1]+i*NH,
        A_log[0]+i*NH, A_log[1]+i*NH, dadt);
    chunk_local<<<dim3(NCH,64),256,0,stream>>>(xbc, dadt, SC, Pc);
    chunk_combine<<<dim3(NE/256),256,0,stream>>>(SC, Pc);
    chunk_apply<<<dim3(NCH,64),256,0,stream>>>(xbc, dadt, SC, Dp[0]+i*NH, Dp[1]+i*NH);
    gate_rms<<<dim3(BT,2),256,0,stream>>>(xbc, zx, rms_w[0]+(size_t)i*DI, rms_w[1]+(size_t)i*DI);
    gemm_nt<2><<<dim3(64,4,2),256,0,stream>>>(zx, out_w[0]+(size_t)i*DM*DI, out_w[1]+(size_t)i*DM*DI,
        h, h, nullptr, BT, DM, DI, DPROJ, (long)BT*DPROJ, (long)BT*DM);
  }

  final_ln<<<dim3(BT),256,0,stream>>>(h, lnout_w, lnout_b, d_out, convMode, flagp);
  (void)needDirect; (void)in_sizes; (void)n_in; (void)out_size;
}

// Round 5
// 1236.790 us; speedup vs baseline: 2.2923x; 1.1051x over previous
//
#include <hip/hip_runtime.h>
#include <hip/hip_bf16.h>
#include <math.h>

// Problem constants
#define BB 4
#define TT 2048
#define BT 8192          // B*T rows
#define DM 512           // d_model
#define DI 1024          // d_inner
#define NH 8
#define HD 128
#define DS 16
#define CONVD 1056       // DI + 2*DSTATE
#define DPROJ 2088       // 2*DI + 2*DSTATE + NHEADS
#define NL 4
#define CL 128           // scan chunk length
#define NCH 16           // TT / CL
#define NE 131072        // 64 dirbh * 2048 state elems

typedef __hip_bfloat16 bf16;
typedef __attribute__((ext_vector_type(8))) short short8;
typedef __attribute__((ext_vector_type(4))) short short4v;
typedef __attribute__((ext_vector_type(4))) float f32x4;

#define AS_G __attribute__((address_space(1)))
#define AS_L __attribute__((address_space(3)))

static __device__ __forceinline__ float b2f_raw(short v){
  union { unsigned u; float f; } c; c.u = ((unsigned)(unsigned short)v) << 16; return c.f;
}

// block-wide reduce of two values across 256 threads (4 waves)
static __device__ __forceinline__ void red2(float& a, float& b, float* sb){
  #pragma unroll
  for (int o = 32; o; o >>= 1){ a += __shfl_down(a, o); b += __shfl_down(b, o); }
  int w = threadIdx.x >> 6;
  if ((threadIdx.x & 63) == 0){ sb[w] = a; sb[4+w] = b; }
  __syncthreads();
  a = sb[0]+sb[1]+sb[2]+sb[3];
  b = sb[4]+sb[5]+sb[6]+sb[7];
}

// ---------------------------------------------------------------------------
// Dtype sniffing (proven-safe; unchanged).
// ---------------------------------------------------------------------------
__global__ __launch_bounds__(256) void detect_dtype(const void* x, int* flagp){
  __shared__ int cnt;
  if (threadIdx.x == 0) cnt = 0;
  __syncthreads();
  const bf16* p = (const bf16*)x;
  int bad = 0;
  for (int i = threadIdx.x; i < 32768; i += 256){
    float v = __bfloat162float(p[i]);
    if (!isfinite(v) || fabsf(v) > 1e4f) bad++;
  }
  atomicAdd(&cnt, bad);
  __syncthreads();
  if (threadIdx.x == 0) *flagp = (cnt > 100) ? 1 : 0;
}

__global__ __launch_bounds__(256) void convert_in(const void* src, bf16* dst, int n,
                                                  const int* flagp){
  int f = *flagp;
  for (int i = blockIdx.x*256 + threadIdx.x; i < n; i += gridDim.x*256){
    if (f) dst[i] = __float2bfloat16(((const float*)src)[i]);
    else   dst[i] = ((const bf16*)src)[i];
  }
}

// ---------------------------------------------------------------------------
// Generic NT GEMM: C[z][M][N] = A[z][M][K(lda)] @ W_z[N][K]^T (bf16, fp32 acc)
// OP=0 plain, OP=1 +bias(X[N]), OP=2 +residual(X[z][M][N], may alias C!),
// OP=3 plain + fp32 side-store of cols >= DPROJ-8 (dt_raw) into aux[z][M][8].
// m97 staging: global_load_lds width=16 (wave-uniform LDS base + lane*16,
// lane i writes row lane>>2, bytes (lane&3)*16 -> contiguous lane order).
// ---------------------------------------------------------------------------
template<int OP>
__global__ __launch_bounds__(256) void gemm_nt(
    const bf16* __restrict__ A, const bf16* __restrict__ W0, const bf16* __restrict__ W1,
    bf16* C, const bf16* X, float* aux,
    int M, int N, int K, int lda, long sA, long sC)
{
  const int z = blockIdx.z;
  const bf16* Az = A + (long)z * sA;
  const bf16* W = z ? W1 : W0;
  const int m0 = blockIdx.x * 128, n0 = blockIdx.y * 128;
  __shared__ __align__(16) bf16 As[128*32];
  __shared__ __align__(16) bf16 Bs[128*32];
  const int tid  = threadIdx.x;
  const int lane = tid & 63, wv = tid >> 6;
  const int wm = wv >> 1, wn = wv & 1;          // wave -> 64x64 quadrant
  const int quad = lane >> 4, l16 = lane & 15;
  const int srow = lane >> 2;                   // staging row within 16-row chunk
  const int skb  = (lane & 3) * 16;             // staging byte offset in 64B row

  f32x4 acc[4][4];
  #pragma unroll
  for (int i=0;i<4;i++)
    #pragma unroll
    for (int j=0;j<4;j++) acc[i][j] = (f32x4){0.f,0.f,0.f,0.f};

  for (int k0 = 0; k0 < K; k0 += 32){
    __syncthreads();                            // prior iter's ds_reads done
    #pragma unroll
    for (int is = 0; is < 2; ++is){
      int r = is*64 + wv*16 + srow;             // 0..127 tile row
      const char* gA = (const char*)(Az + (long)(m0 + r)*lda + k0) + skb;
      char* lA = (char*)As + (long)(is*64 + wv*16)*64;
      __builtin_amdgcn_global_load_lds((const AS_G void*)gA, (AS_L void*)lA, 16, 0, 0);
      int rn = n0 + r; rn = rn < N ? rn : N-1;  // clamp OOB weight rows (cols >= N never stored)
      const char* gB = (const char*)(W + (long)rn*K + k0) + skb;
      char* lB = (char*)Bs + (long)(is*64 + wv*16)*64;
      __builtin_amdgcn_global_load_lds((const AS_G void*)gB, (AS_L void*)lB, 16, 0, 0);
    }
    __syncthreads();                            // drains vmcnt before barrier
    short8 af[4], bfr[4];
    #pragma unroll
    for (int mi=0;mi<4;mi++) af[mi]  = *(const short8*)((const char*)As + (long)(wm*64+mi*16+l16)*64 + quad*16);
    #pragma unroll
    for (int ni=0;ni<4;ni++) bfr[ni] = *(const short8*)((const char*)Bs + (long)(wn*64+ni*16+l16)*64 + quad*16);
    #pragma unroll
    for (int mi=0;mi<4;mi++)
      #pragma unroll
      for (int ni=0;ni<4;ni++)
        acc[mi][ni] = __builtin_amdgcn_mfma_f32_16x16x32_bf16(af[mi], bfr[ni], acc[mi][ni], 0, 0, 0);
  }

  bf16* Cz = C + (long)z * sC;
  const bf16* Xz = (OP==2) ? (X + (long)z * sC) : X;
  #pragma unroll
  for (int mi=0;mi<4;mi++){
    #pragma unroll
    for (int ni=0;ni<4;ni++){
      #pragma unroll
      for (int r=0;r<4;r++){
        int row = m0 + wm*64 + mi*16 + quad*4 + r;
        int col = n0 + wn*64 + ni*16 + l16;
        if (col < N){
          float v = acc[mi][ni][r];
          if (OP==1) v += __bfloat162float(X[col]);
          if (OP==2) v += __bfloat162float(Xz[(long)row*N + col]);
          Cz[(long)row*N + col] = __float2bfloat16(v);
          if (OP==3 && col >= DPROJ-8)
            aux[(long)z*BT*8 + (long)row*8 + (col-(DPROJ-8))] = v;
        }
      }
    }
  }
}

// ---------------------------------------------------------------------------
// LayerNorm of embed output (512) -> h_f and time-reversed h_b
// ---------------------------------------------------------------------------
__global__ __launch_bounds__(256) void embed_ln(const bf16* __restrict__ hp,
    const bf16* __restrict__ w, const bf16* __restrict__ bb, bf16* __restrict__ h)
{
  __shared__ float sb[8];
  int bt = blockIdx.x; int b = bt >> 11, t = bt & 2047;
  const bf16* r = hp + (long)bt*DM;
  int c0 = threadIdx.x, c1 = threadIdx.x + 256;
  float v0 = __bfloat162float(r[c0]);
  float v1 = __bfloat162float(r[c1]);
  float s = v0+v1, ss = v0*v0+v1*v1;
  red2(s, ss, sb);
  float m = s / DM;
  float var = ss / DM - m*m;
  float rs = rsqrtf(fmaxf(var, 0.f) + 1e-5f);
  float a0 = (v0-m)*rs*__bfloat162float(w[c0]) + __bfloat162float(bb[c0]);
  float a1 = (v1-m)*rs*__bfloat162float(w[c1]) + __bfloat162float(bb[c1]);
  bf16* o0 = h + (long)bt*DM;
  bf16* o1 = h + ((long)BT + (long)b*TT + (TT-1-t)) * DM;
  o0[c0] = __float2bfloat16(a0); o0[c1] = __float2bfloat16(a1);
  o1[c0] = __float2bfloat16(a0); o1[c1] = __float2bfloat16(a1);
}

// ---------------------------------------------------------------------------
// Causal depthwise conv (K=4) + bias + SiLU — vectorized: 4 channels/thread,
// short4 activation loads, short8 weight loads. Math identical to round 4.
// ---------------------------------------------------------------------------
__global__ __launch_bounds__(256) void conv_silu(const bf16* __restrict__ zx,
    const bf16* __restrict__ cw0, const bf16* __restrict__ cw1,
    const bf16* __restrict__ cb0, const bf16* __restrict__ cb1,
    bf16* __restrict__ xbc)
{
  int bt = blockIdx.x, dir = blockIdx.y;
  int t = bt & 2047;
  const bf16* cw = dir ? cw1 : cw0;
  const bf16* cb = dir ? cb1 : cb0;
  const bf16* zr = zx + ((long)dir*BT + bt)*DPROJ + DI;  // row t, col 1024
  bf16* orow = xbc + ((long)dir*BT + bt)*CONVD;
  for (int cg = threadIdx.x; cg < CONVD/4; cg += 256){   // 264 groups of 4 ch
    int c = cg*4;
    short8 w01 = *(const short8*)(cw + c*4);       // ch c (j0..3), ch c+1
    short8 w23 = *(const short8*)(cw + c*4 + 8);   // ch c+2, ch c+3
    short4v bi = *(const short4v*)(cb + c);
    float acc[4];
    #pragma unroll
    for (int k=0;k<4;k++) acc[k] = b2f_raw(bi[k]);
    #pragma unroll
    for (int j=0;j<4;j++){
      if (t - 3 + j >= 0){
        short4v xv = *(const short4v*)(zr + (long)(j-3)*DPROJ + c);
        acc[0] = fmaf(b2f_raw(w01[j]),   b2f_raw(xv[0]), acc[0]);
        acc[1] = fmaf(b2f_raw(w01[4+j]), b2f_raw(xv[1]), acc[1]);
        acc[2] = fmaf(b2f_raw(w23[j]),   b2f_raw(xv[2]), acc[2]);
        acc[3] = fmaf(b2f_raw(w23[4+j]), b2f_raw(xv[3]), acc[3]);
      }
    }
    short4v ov;
    #pragma unroll
    for (int k=0;k<4;k++){
      float sg = 1.f / (1.f + expf(-acc[k]));
      ov[k] = (short)__bfloat16_as_ushort(__float2bfloat16(acc[k] * sg));
    }
    *(short4v*)(orow + c) = ov;
  }
}

// ---------------------------------------------------------------------------
// dt = softplus(dt_raw + bias); dA = exp(-exp(A_log)*dt); packed as float2
// ---------------------------------------------------------------------------
__global__ __launch_bounds__(256) void dt_kernel(const float* __restrict__ draw,
    const bf16* __restrict__ db0, const bf16* __restrict__ db1,
    const bf16* __restrict__ al0, const bf16* __restrict__ al1,
    float2* __restrict__ dadt)
{
  int idx = blockIdx.x*256 + threadIdx.x;   // 2*8192*8 = 131072 total
  int dir = idx >> 16, r = idx & 65535;
  int bt = r >> 3, h = r & 7;
  int b = bt >> 11, t = bt & 2047;
  float x = draw[idx] + __bfloat162float((dir?db1:db0)[h]);
  float sp = (x > 20.f) ? x : log1pf(expf(x));
  float a = expf(-expf(__bfloat162float((dir?al1:al0)[h])) * sp);
  long o = (((long)dir*BB + b)*NH + h)*TT + t;
  float2 v; v.x = a; v.y = sp;
  dadt[o] = v;
}

// ---------------------------------------------------------------------------
// Chunked selective scan (SSD) — exact recombination (scalar transition).
// ---------------------------------------------------------------------------
#define SC_LOAD(X,BV,CV,DD,T0) do{ \
  _Pragma("unroll") \
  for (int _i=0;_i<4;_i++){ \
    const bf16* _rr = xr + (long)((T0)+_i)*CONVD; \
    X[_i]  = __bfloat162float(_rr[h*HD + p]); \
    BV[_i] = *(const short8*)(_rr + DI + half*8); \
    CV[_i] = *(const short8*)(_rr + DI + DS + half*8); \
    DD[_i] = ddr[(T0)+_i]; \
  } }while(0)

#define SC_STEP(X,BV,CV,DD,T0) do{ \
  _Pragma("unroll") \
  for (int _i=0;_i<4;_i++){ \
    float _dav = DD[_i].x, _dtv = DD[_i].y; \
    float _xdt = X[_i] * _dtv; \
    float _acc = 0.f; \
    _Pragma("unroll") \
    for (int _n=0;_n<8;_n++){ \
      s[_n] = fmaf(_dav, s[_n], _xdt * b2f_raw(BV[_i][_n])); \
      _acc  = fmaf(s[_n], b2f_raw(CV[_i][_n]), _acc); } \
    _acc += __shfl_xor(_acc, 1); \
    if (!half) xw[(long)((T0)+_i)*CONVD + h*HD + p] = __float2bfloat16(_acc + Dv*X[_i]); \
  } }while(0)

#define CH_LOAD(X,BV,DD,T0) do{ \
  _Pragma("unroll") \
  for (int _i=0;_i<4;_i++){ \
    const bf16* _rr = xr + (long)((T0)+_i)*CONVD; \
    X[_i]  = __bfloat162float(_rr[h*HD + p]); \
    BV[_i] = *(const short8*)(_rr + DI + half*8); \
    DD[_i] = ddr[(T0)+_i]; \
  } }while(0)

#define CH_STEP(X,BV,DD) do{ \
  _Pragma("unroll") \
  for (int _i=0;_i<4;_i++){ \
    float _dav = DD[_i].x, _dtv = DD[_i].y; \
    float _xdt = X[_i] * _dtv; \
    _Pragma("unroll") \
    for (int _n=0;_n<8;_n++) \
      s[_n] = fmaf(_dav, s[_n], _xdt * b2f_raw(BV[_i][_n])); \
    pacc *= _dav; \
  } }while(0)

__global__ __launch_bounds__(256) void chunk_local(const bf16* __restrict__ xbc,
    const float2* __restrict__ dadt, float* __restrict__ SC, float* __restrict__ Pc)
{
  int c = blockIdx.x, dbh = blockIdx.y;
  int dir = dbh >> 5, b = (dbh >> 3) & 3, h = dbh & 7;
  int tid = threadIdx.x, p = tid >> 1, half = tid & 1;
  const bf16* xr = xbc + ((long)dir*BT + (long)b*TT) * CONVD;
  const float2* ddr = dadt + (((long)dir*BB + b)*NH + h)*TT;
  float s[8];
  #pragma unroll
  for (int n=0;n<8;n++) s[n] = 0.f;
  float pacc = 1.f;
  const int c0 = c*CL;

  float xA[4], xB2[4];
  short8 BA[4], BB2[4];
  float2 dA_[4], dB_[4];

  CH_LOAD(xA,BA,dA_, c0);
  for (int t0 = c0; t0 < c0+CL; t0 += 8){
    CH_LOAD(xB2,BB2,dB_, t0+4);
    CH_STEP(xA,BA,dA_);
    if (t0+8 < c0+CL) CH_LOAD(xA,BA,dA_, t0+8);
    CH_STEP(xB2,BB2,dB_);
  }
  long e = (long)dbh*2048 + p*16 + half*8;
  #pragma unroll
  for (int n=0;n<8;n++) SC[(long)c*NE + e + n] = s[n];
  if (tid == 0) Pc[dbh*NCH + c] = pacc;
}

__global__ __launch_bounds__(256) void chunk_combine(float* __restrict__ SC,
    const float* __restrict__ Pc)
{
  int e = blockIdx.x*256 + threadIdx.x;   // 131072 total
  int dbh = e >> 11;
  float s = 0.f;
  #pragma unroll
  for (int c=0;c<NCH;c++){
    float tmp = SC[(long)c*NE + e];
    SC[(long)c*NE + e] = s;               // exclusive scan in place -> S_init
    s = Pc[dbh*NCH + c]*s + tmp;
  }
}

__global__ __launch_bounds__(256) void chunk_apply(bf16* __restrict__ xbc,
    const float2* __restrict__ dadt, const float* __restrict__ SC,
    const bf16* __restrict__ D0, const bf16* __restrict__ D1)
{
  int c = blockIdx.x, dbh = blockIdx.y;
  int dir = dbh >> 5, b = (dbh >> 3) & 3, h = dbh & 7;
  int tid = threadIdx.x, p = tid >> 1, half = tid & 1;
  const bf16* xr = xbc + ((long)dir*BT + (long)b*TT) * CONVD;
  bf16* xw = xbc + ((long)dir*BT + (long)b*TT) * CONVD;
  const float2* ddr = dadt + (((long)dir*BB + b)*NH + h)*TT;
  float Dv = __bfloat162float(dir ? D1[h] : D0[h]);
  long e = (long)dbh*2048 + p*16 + half*8;
  float s[8];
  #pragma unroll
  for (int n=0;n<8;n++) s[n] = SC[(long)c*NE + e + n];
  const int c0 = c*CL;

  float xA[4], xB2[4];
  short8 BA[4], BB2[4], CA[4], CB2[4];
  float2 dA_[4], dB_[4];

  SC_LOAD(xA,BA,CA,dA_, c0);
  for (int t0 = c0; t0 < c0+CL; t0 += 8){
    SC_LOAD(xB2,BB2,CB2,dB_, t0+4);
    SC_STEP(xA,BA,CA,dA_, t0);
    if (t0+8 < c0+CL) SC_LOAD(xA,BA,CA,dA_, t0+8);
    SC_STEP(xB2,BB2,CB2,dB_, t0+4);
  }
}

// ---------------------------------------------------------------------------
// g = y*silu(z), gated RMSNorm; in place into z-cols of zx. Vectorized short4.
// ---------------------------------------------------------------------------
__global__ __launch_bounds__(256) void gate_rms(const bf16* __restrict__ xbc, bf16* zx,
    const bf16* __restrict__ rw0, const bf16* __restrict__ rw1)
{
  __shared__ float sb[8];
  int bt = blockIdx.x, dir = blockIdx.y;
  const bf16* yr = xbc + ((long)dir*BT + bt)*CONVD;
  bf16* zr = zx + ((long)dir*BT + bt)*DPROJ;
  const bf16* rw = dir ? rw1 : rw0;
  int c = threadIdx.x*4;                        // 256*4 = 1024 = DI exactly
  short4v yv4 = *(const short4v*)(yr + c);
  short4v zv4 = *(const short4v*)(zr + c);
  short4v rw4 = *(const short4v*)(rw + c);
  float gv[4], ss = 0.f, dummy = 0.f;
  #pragma unroll
  for (int k=0;k<4;k++){
    float yv = b2f_raw(yv4[k]);
    float zv = b2f_raw(zv4[k]);
    float sg = 1.f/(1.f+expf(-zv));
    gv[k] = yv * zv * sg;
    ss += gv[k]*gv[k];
  }
  red2(ss, dummy, sb);
  float sc = rsqrtf(ss / DI + 1e-5f);
  short4v ov;
  #pragma unroll
  for (int k=0;k<4;k++)
    ov[k] = (short)__bfloat16_as_ushort(__float2bfloat16(gv[k]*sc*b2f_raw(rw4[k])));
  *(short4v*)(zr + c) = ov;
}

// ---------------------------------------------------------------------------
// Final LN over concat(h_f[b,t], h_b[b,T-1-t]) (1024) -> d_out
// ---------------------------------------------------------------------------
__global__ __launch_bounds__(256) void final_ln(const bf16* __restrict__ h,
    const bf16* __restrict__ lw, const bf16* __restrict__ lb, void* out,
    int mode, const int* flagp)
{
  __shared__ float sb[8];
  int bt = blockIdx.x; int b = bt >> 11, t = bt & 2047;
  int f32out = mode ? *flagp : 0;
  const bf16* rf = h + (long)bt*DM;
  const bf16* rb = h + ((long)BT + (long)b*TT + (TT-1-t))*DM;
  float v[4], s = 0.f, ss = 0.f;
  #pragma unroll
  for (int i=0;i<4;i++){
    int c = threadIdx.x + i*256;
    v[i] = __bfloat162float(c < DM ? rf[c] : rb[c-DM]);
    s += v[i]; ss += v[i]*v[i];
  }
  red2(s, ss, sb);
  float m = s / (2*DM);
  float var = ss / (2*DM) - m*m;
  float rs = rsqrtf(fmaxf(var, 0.f) + 1e-5f);
  #pragma unroll
  for (int i=0;i<4;i++){
    int c = threadIdx.x + i*256;
    float o = (v[i]-m)*rs*__bfloat162float(lw[c]) + __bfloat162float(lb[c]);
    if (f32out) ((float*)out)[(long)bt*(2*DM) + c] = o;
    else        ((bf16*)out)[(long)bt*(2*DM) + c] = __float2bfloat16(o);
  }
}

// ---------------------------------------------------------------------------
extern "C" void kernel_launch(void* const* d_in, const int* in_sizes, int n_in,
                              void* d_out, int out_size, void* d_ws, size_t ws_size,
                              hipStream_t stream)
{
  char* wsp = (char*)d_ws;
  auto take = [&](size_t bytes){ char* p = wsp; wsp += (bytes + 63) & ~(size_t)63; return p; };
  int*   flagp = (int*)  take(4);
  bf16*  h     = (bf16*) take((size_t)2*BT*DM*2);      // 16.78 MB
  bf16*  zx    = (bf16*) take((size_t)2*BT*DPROJ*2);   // 68.42 MB (z gated in place)
  bf16*  xbc   = (bf16*) take((size_t)2*BT*CONVD*2);   // 34.60 MB (y scanned in place)
  float2* dadt = (float2*)take((size_t)2*BB*NH*TT*8);  // 1.05 MB
  float* draw  = (float*)take((size_t)2*BT*NH*4);      // 0.52 MB
  float* Pc    = (float*)take((size_t)64*NCH*4);       // 4 KB
  float* SC    = (float*)take((size_t)NCH*NE*4);       // 8.39 MB chunk states
  size_t needDirect = (size_t)(wsp - (char*)d_ws);     // ~129.8 MB

  static const int cnt[23] = {
    BT*256, DM*256, DM, DM, DM, 2*DM, 2*DM,
    NL*DPROJ*DM, NL*CONVD*4, NL*CONVD, NL*NH, NL*NH, NL*NH, NL*DI, NL*DM*DI,
    NL*DPROJ*DM, NL*CONVD*4, NL*CONVD, NL*NH, NL*NH, NL*NH, NL*DI, NL*DM*DI };
  bf16* canon[23];
  for (int i = 0; i < 23; ++i) canon[i] = (bf16*)take((size_t)cnt[i]*2);
  size_t needFull = (size_t)(wsp - (char*)d_ws);       // ~167.9 MB

  const int convMode = (ws_size >= needFull) ? 1 : 0;

  const bf16* in[23];
  if (convMode){
    detect_dtype<<<1,256,0,stream>>>(d_in[0], flagp);
    for (int i = 0; i < 23; ++i){
      int grid = (cnt[i] + 255)/256; if (grid > 2048) grid = 2048;
      convert_in<<<grid,256,0,stream>>>(d_in[i], canon[i], cnt[i], flagp);
      in[i] = canon[i];
    }
  } else {
    for (int i = 0; i < 23; ++i) in[i] = (const bf16*)d_in[i];
  }

  const bf16* x       = in[0];
  const bf16* embed_w = in[1];
  const bf16* embed_b = in[2];
  const bf16* ln1_w   = in[3];
  const bf16* ln1_b   = in[4];
  const bf16* lnout_w = in[5];
  const bf16* lnout_b = in[6];
  const bf16* in_w[2]   = {in[7],  in[15]};
  const bf16* conv_w[2] = {in[8],  in[16]};
  const bf16* conv_b[2] = {in[9],  in[17]};
  const bf16* dt_b[2]   = {in[10], in[18]};
  const bf16* A_log[2]  = {in[11], in[19]};
  const bf16* Dp[2]     = {in[12], in[20]};
  const bf16* rms_w[2]  = {in[13], in[21]};
  const bf16* out_w[2]  = {in[14], in[22]};

  bf16* hpre = xbc;   // embed output parks in xbc (free until layer-0 conv)

  gemm_nt<1><<<dim3(64,4,1),256,0,stream>>>(x, embed_w, embed_w, hpre, embed_b, nullptr,
                                            BT, DM, 256, 256, 0, 0);
  embed_ln<<<dim3(BT),256,0,stream>>>(hpre, ln1_w, ln1_b, h);

  for (int i = 0; i < NL; ++i){
    gemm_nt<3><<<dim3(64,17,2),256,0,stream>>>(h, in_w[0]+(size_t)i*DPROJ*DM, in_w[1]+(size_t)i*DPROJ*DM,
        zx, nullptr, draw, BT, DPROJ, DM, DM, (long)BT*DM, (long)BT*DPROJ);
    conv_silu<<<dim3(BT,2),256,0,stream>>>(zx, conv_w[0]+(size_t)i*CONVD*4, conv_w[1]+(size_t)i*CONVD*4,
        conv_b[0]+(size_t)i*CONVD, conv_b[1]+(size_t)i*CONVD, xbc);
    dt_kernel<<<dim3(512),256,0,stream>>>(draw, dt_b[0]+i*NH, dt_b[1]+i*NH,
        A_log[0]+i*NH, A_log[1]+i*NH, dadt);
    chunk_local<<<dim3(NCH,64),256,0,stream>>>(xbc, dadt, SC, Pc);
    chunk_combine<<<dim3(NE/256),256,0,stream>>>(SC, Pc);
    chunk_apply<<<dim3(NCH,64),256,0,stream>>>(xbc, dadt, SC, Dp[0]+i*NH, Dp[1]+i*NH);
    gate_rms<<<dim3(BT,2),256,0,stream>>>(xbc, zx, rms_w[0]+(size_t)i*DI, rms_w[1]+(size_t)i*DI);
    gemm_nt<2><<<dim3(64,4,2),256,0,stream>>>(zx, out_w[0]+(size_t)i*DM*DI, out_w[1]+(size_t)i*DM*DI,
        h, h, nullptr, BT, DM, DI, DPROJ, (long)BT*DPROJ, (long)BT*DM);
  }

  final_ln<<<dim3(BT),256,0,stream>>>(h, lnout_w, lnout_b, d_out, convMode, flagp);
  (void)needDirect; (void)in_sizes; (void)n_in; (void)out_size;
}

// Round 6
// 1211.898 us; speedup vs baseline: 2.3394x; 1.0205x over previous
//
#include <hip/hip_runtime.h>
#include <hip/hip_bf16.h>
#include <math.h>

// Problem constants
#define BB 4
#define TT 2048
#define BT 8192          // B*T rows
#define DM 512           // d_model
#define DI 1024          // d_inner
#define NH 8
#define HD 128
#define DS 16
#define CONVD 1056       // DI + 2*DSTATE
#define DPROJ 2088       // 2*DI + 2*DSTATE + NHEADS
#define NL 4
#define CL 128           // scan chunk length
#define NCH 16           // TT / CL
#define NE 131072        // 64 dirbh * 2048 state elems

typedef __hip_bfloat16 bf16;
typedef __attribute__((ext_vector_type(8))) short short8;
typedef __attribute__((ext_vector_type(4))) short short4v;
typedef __attribute__((ext_vector_type(4))) float f32x4;

#define AS_G __attribute__((address_space(1)))
#define AS_L __attribute__((address_space(3)))

static __device__ __forceinline__ float b2f_raw(short v){
  union { unsigned u; float f; } c; c.u = ((unsigned)(unsigned short)v) << 16; return c.f;
}
static __device__ __forceinline__ float u32_lo(unsigned u){
  union { unsigned u; float f; } c; c.u = u << 16; return c.f;
}
static __device__ __forceinline__ float u32_hi(unsigned u){
  union { unsigned u; float f; } c; c.u = u & 0xffff0000u; return c.f;
}
static __device__ __forceinline__ unsigned pack_bf16x2(float a, float b){
  unsigned lo = __bfloat16_as_ushort(__float2bfloat16(a));
  unsigned hi = __bfloat16_as_ushort(__float2bfloat16(b));
  return lo | (hi << 16);
}

// block-wide reduce of two values across 256 threads (4 waves)
static __device__ __forceinline__ void red2(float& a, float& b, float* sb){
  #pragma unroll
  for (int o = 32; o; o >>= 1){ a += __shfl_down(a, o); b += __shfl_down(b, o); }
  int w = threadIdx.x >> 6;
  if ((threadIdx.x & 63) == 0){ sb[w] = a; sb[4+w] = b; }
  __syncthreads();
  a = sb[0]+sb[1]+sb[2]+sb[3];
  b = sb[4]+sb[5]+sb[6]+sb[7];
}

// ---------------------------------------------------------------------------
// Dtype sniffing (proven-safe; unchanged).
// ---------------------------------------------------------------------------
__global__ __launch_bounds__(256) void detect_dtype(const void* x, int* flagp){
  __shared__ int cnt;
  if (threadIdx.x == 0) cnt = 0;
  __syncthreads();
  const bf16* p = (const bf16*)x;
  int bad = 0;
  for (int i = threadIdx.x; i < 32768; i += 256){
    float v = __bfloat162float(p[i]);
    if (!isfinite(v) || fabsf(v) > 1e4f) bad++;
  }
  atomicAdd(&cnt, bad);
  __syncthreads();
  if (threadIdx.x == 0) *flagp = (cnt > 100) ? 1 : 0;
}

__global__ __launch_bounds__(256) void convert_in(const void* src, bf16* dst, int n,
                                                  const int* flagp){
  int f = *flagp;
  for (int i = blockIdx.x*256 + threadIdx.x; i < n; i += gridDim.x*256){
    if (f) dst[i] = __float2bfloat16(((const float*)src)[i]);
    else   dst[i] = ((const bf16*)src)[i];
  }
}

// ---------------------------------------------------------------------------
// Generic NT GEMM: C[z][M][N] = A[z][M][K(lda)] @ W_z[N][K]^T (bf16, fp32 acc)
// Template MR in {128, 256}: M-tile rows. MR=256: 4 waves stacked in M, each
// owning 64 rows x 128 cols (acc 4x8) -> 2x MFMA per barrier-drain pair vs
// MR=128 (K=512 GEMM is overhead-bound, not staging-bound: round-5 A/B).
// OP=0 plain, OP=1 +bias(X[N]), OP=2 +residual(X[z][M][N], may alias C!),
// OP=3 plain + fp32 side-store of cols >= DPROJ-8 (dt_raw) into aux[z][M][8].
// ---------------------------------------------------------------------------
template<int OP, int MR>
__global__ __launch_bounds__(256,2) void gemm_nt(
    const bf16* __restrict__ A, const bf16* __restrict__ W0, const bf16* __restrict__ W1,
    bf16* C, const bf16* X, float* aux,
    int M, int N, int K, int lda, long sA, long sC)
{
  constexpr int NF = (MR == 256) ? 8 : 4;     // n-frags per wave
  const int z = blockIdx.z;
  const bf16* Az = A + (long)z * sA;
  const bf16* W = z ? W1 : W0;
  const int m0 = blockIdx.x * MR, n0 = blockIdx.y * 128;
  __shared__ __align__(16) bf16 As[MR*32];
  __shared__ __align__(16) bf16 Bs[128*32];
  const int tid  = threadIdx.x;
  const int lane = tid & 63, wv = tid >> 6;
  const int wmB = (MR == 256) ? wv*64 : (wv >> 1)*64;   // wave row base in tile
  const int wnB = (MR == 256) ? 0     : (wv & 1)*64;    // wave col base in tile
  const int quad = lane >> 4, l16 = lane & 15;
  const int srow = lane >> 2;                 // staging row within 16-row chunk
  const int skb  = (lane & 3) * 16;           // staging byte offset in 64B row

  f32x4 acc[4][NF];
  #pragma unroll
  for (int i=0;i<4;i++)
    #pragma unroll
    for (int j=0;j<NF;j++) acc[i][j] = (f32x4){0.f,0.f,0.f,0.f};

  for (int k0 = 0; k0 < K; k0 += 32){
    __syncthreads();                          // prior iter's ds_reads done
    #pragma unroll
    for (int is = 0; is < MR/64; ++is){       // A tile: MR rows
      int r = is*64 + wv*16 + srow;
      const char* gA = (const char*)(Az + (long)(m0 + r)*lda + k0) + skb;
      char* lA = (char*)As + (long)(is*64 + wv*16)*64;
      __builtin_amdgcn_global_load_lds((const AS_G void*)gA, (AS_L void*)lA, 16, 0, 0);
    }
    #pragma unroll
    for (int is = 0; is < 2; ++is){           // B tile: 128 rows
      int r = is*64 + wv*16 + srow;
      int rn = n0 + r; rn = rn < N ? rn : N-1;  // clamp OOB weight rows
      const char* gB = (const char*)(W + (long)rn*K + k0) + skb;
      char* lB = (char*)Bs + (long)(is*64 + wv*16)*64;
      __builtin_amdgcn_global_load_lds((const AS_G void*)gB, (AS_L void*)lB, 16, 0, 0);
    }
    __syncthreads();                          // drains vmcnt before barrier
    short8 af[4], bfr[NF];
    #pragma unroll
    for (int mi=0;mi<4;mi++)  af[mi]  = *(const short8*)((const char*)As + (long)(wmB+mi*16+l16)*64 + quad*16);
    #pragma unroll
    for (int ni=0;ni<NF;ni++) bfr[ni] = *(const short8*)((const char*)Bs + (long)(wnB+ni*16+l16)*64 + quad*16);
    #pragma unroll
    for (int mi=0;mi<4;mi++)
      #pragma unroll
      for (int ni=0;ni<NF;ni++)
        acc[mi][ni] = __builtin_amdgcn_mfma_f32_16x16x32_bf16(af[mi], bfr[ni], acc[mi][ni], 0, 0, 0);
  }

  bf16* Cz = C + (long)z * sC;
  const bf16* Xz = (OP==2) ? (X + (long)z * sC) : X;
  #pragma unroll
  for (int mi=0;mi<4;mi++){
    #pragma unroll
    for (int ni=0;ni<NF;ni++){
      #pragma unroll
      for (int r=0;r<4;r++){
        int row = m0 + wmB + mi*16 + quad*4 + r;
        int col = n0 + wnB + ni*16 + l16;
        if (col < N){
          float v = acc[mi][ni][r];
          if (OP==1) v += __bfloat162float(X[col]);
          if (OP==2) v += __bfloat162float(Xz[(long)row*N + col]);
          Cz[(long)row*N + col] = __float2bfloat16(v);
          if (OP==3 && col >= DPROJ-8)
            aux[(long)z*BT*8 + (long)row*8 + (col-(DPROJ-8))] = v;
        }
      }
    }
  }
}

// ---------------------------------------------------------------------------
// LayerNorm of embed output (512) -> h_f and time-reversed h_b
// ---------------------------------------------------------------------------
__global__ __launch_bounds__(256) void embed_ln(const bf16* __restrict__ hp,
    const bf16* __restrict__ w, const bf16* __restrict__ bb, bf16* __restrict__ h)
{
  __shared__ float sb[8];
  int bt = blockIdx.x; int b = bt >> 11, t = bt & 2047;
  const bf16* r = hp + (long)bt*DM;
  int c0 = threadIdx.x, c1 = threadIdx.x + 256;
  float v0 = __bfloat162float(r[c0]);
  float v1 = __bfloat162float(r[c1]);
  float s = v0+v1, ss = v0*v0+v1*v1;
  red2(s, ss, sb);
  float m = s / DM;
  float var = ss / DM - m*m;
  float rs = rsqrtf(fmaxf(var, 0.f) + 1e-5f);
  float a0 = (v0-m)*rs*__bfloat162float(w[c0]) + __bfloat162float(bb[c0]);
  float a1 = (v1-m)*rs*__bfloat162float(w[c1]) + __bfloat162float(bb[c1]);
  bf16* o0 = h + (long)bt*DM;
  bf16* o1 = h + ((long)BT + (long)b*TT + (TT-1-t)) * DM;
  o0[c0] = __float2bfloat16(a0); o0[c1] = __float2bfloat16(a1);
  o1[c0] = __float2bfloat16(a0); o1[c1] = __float2bfloat16(a1);
}

// ---------------------------------------------------------------------------
// Causal depthwise conv (K=4) + bias + SiLU — vectorized (round 5)
// ---------------------------------------------------------------------------
__global__ __launch_bounds__(256) void conv_silu(const bf16* __restrict__ zx,
    const bf16* __restrict__ cw0, const bf16* __restrict__ cw1,
    const bf16* __restrict__ cb0, const bf16* __restrict__ cb1,
    bf16* __restrict__ xbc)
{
  int bt = blockIdx.x, dir = blockIdx.y;
  int t = bt & 2047;
  const bf16* cw = dir ? cw1 : cw0;
  const bf16* cb = dir ? cb1 : cb0;
  const bf16* zr = zx + ((long)dir*BT + bt)*DPROJ + DI;  // row t, col 1024
  bf16* orow = xbc + ((long)dir*BT + bt)*CONVD;
  for (int cg = threadIdx.x; cg < CONVD/4; cg += 256){   // 264 groups of 4 ch
    int c = cg*4;
    short8 w01 = *(const short8*)(cw + c*4);       // ch c (j0..3), ch c+1
    short8 w23 = *(const short8*)(cw + c*4 + 8);   // ch c+2, ch c+3
    short4v bi = *(const short4v*)(cb + c);
    float acc[4];
    #pragma unroll
    for (int k=0;k<4;k++) acc[k] = b2f_raw(bi[k]);
    #pragma unroll
    for (int j=0;j<4;j++){
      if (t - 3 + j >= 0){
        short4v xv = *(const short4v*)(zr + (long)(j-3)*DPROJ + c);
        acc[0] = fmaf(b2f_raw(w01[j]),   b2f_raw(xv[0]), acc[0]);
        acc[1] = fmaf(b2f_raw(w01[4+j]), b2f_raw(xv[1]), acc[1]);
        acc[2] = fmaf(b2f_raw(w23[j]),   b2f_raw(xv[2]), acc[2]);
        acc[3] = fmaf(b2f_raw(w23[4+j]), b2f_raw(xv[3]), acc[3]);
      }
    }
    short4v ov;
    #pragma unroll
    for (int k=0;k<4;k++){
      float sg = 1.f / (1.f + expf(-acc[k]));
      ov[k] = (short)__bfloat16_as_ushort(__float2bfloat16(acc[k] * sg));
    }
    *(short4v*)(orow + c) = ov;
  }
}

// ---------------------------------------------------------------------------
// dt = softplus(dt_raw + bias); dA = exp(-exp(A_log)*dt); packed as float2
// ---------------------------------------------------------------------------
__global__ __launch_bounds__(256) void dt_kernel(const float* __restrict__ draw,
    const bf16* __restrict__ db0, const bf16* __restrict__ db1,
    const bf16* __restrict__ al0, const bf16* __restrict__ al1,
    float2* __restrict__ dadt)
{
  int idx = blockIdx.x*256 + threadIdx.x;   // 2*8192*8 = 131072 total
  int dir = idx >> 16, r = idx & 65535;
  int bt = r >> 3, h = r & 7;
  int b = bt >> 11, t = bt & 2047;
  float x = draw[idx] + __bfloat162float((dir?db1:db0)[h]);
  float sp = (x > 20.f) ? x : log1pf(expf(x));
  float a = expf(-expf(__bfloat162float((dir?al1:al0)[h])) * sp);
  long o = (((long)dir*BB + b)*NH + h)*TT + t;
  float2 v; v.x = a; v.y = sp;
  dadt[o] = v;
}

// ---------------------------------------------------------------------------
// Chunked selective scan (SSD), wave-per-(chunk,dbh) layout:
// lane owns p in {2*lane, 2*lane+1} x all 16 n -> 64 FMA per ~12 overhead
// instructions, coalesced u32 x-loads, no shfl, no barriers.
// Block = 4 waves = 4 dbh values; grid (NCH, 16).
// ---------------------------------------------------------------------------
#define CLG_LOAD(G, T0) do{ \
  _Pragma("unroll") \
  for (int _i=0;_i<4;_i++){ \
    const bf16* _rr = xr + (long)((T0)+_i)*CONVD; \
    G##x[_i]  = *(const unsigned*)(_rr + xoff); \
    G##B0[_i] = *(const short8*)(_rr + DI); \
    G##B1[_i] = *(const short8*)(_rr + DI + 8); \
    G##d[_i]  = ddr[(T0)+_i]; \
  } }while(0)

#define CLG_STEP(G) do{ \
  _Pragma("unroll") \
  for (int _i=0;_i<4;_i++){ \
    float _da = G##d[_i].x, _dt = G##d[_i].y; \
    float _x0 = u32_lo(G##x[_i]), _x1 = u32_hi(G##x[_i]); \
    float _xd0 = _x0*_dt, _xd1 = _x1*_dt; \
    _Pragma("unroll") \
    for (int _n=0;_n<8;_n++){ \
      float _b = b2f_raw(G##B0[_i][_n]); \
      s0[_n] = fmaf(_da, s0[_n], _xd0*_b); \
      s1[_n] = fmaf(_da, s1[_n], _xd1*_b); \
      float _b2 = b2f_raw(G##B1[_i][_n]); \
      s0[8+_n] = fmaf(_da, s0[8+_n], _xd0*_b2); \
      s1[8+_n] = fmaf(_da, s1[8+_n], _xd1*_b2); \
    } \
    pacc *= _da; \
  } }while(0)

#define CAG_LOAD(G, T0) do{ \
  _Pragma("unroll") \
  for (int _i=0;_i<4;_i++){ \
    const bf16* _rr = xr + (long)((T0)+_i)*CONVD; \
    G##x[_i]  = *(const unsigned*)(_rr + xoff); \
    G##B0[_i] = *(const short8*)(_rr + DI); \
    G##B1[_i] = *(const short8*)(_rr + DI + 8); \
    G##C0[_i] = *(const short8*)(_rr + DI + DS); \
    G##C1[_i] = *(const short8*)(_rr + DI + DS + 8); \
    G##d[_i]  = ddr[(T0)+_i]; \
  } }while(0)

#define CAG_STEP(G, T0) do{ \
  _Pragma("unroll") \
  for (int _i=0;_i<4;_i++){ \
    float _da = G##d[_i].x, _dt = G##d[_i].y; \
    float _x0 = u32_lo(G##x[_i]), _x1 = u32_hi(G##x[_i]); \
    float _xd0 = _x0*_dt, _xd1 = _x1*_dt; \
    float _a0 = 0.f, _a1 = 0.f; \
    _Pragma("unroll") \
    for (int _n=0;_n<8;_n++){ \
      float _b = b2f_raw(G##B0[_i][_n]); \
      float _c = b2f_raw(G##C0[_i][_n]); \
      s0[_n] = fmaf(_da, s0[_n], _xd0*_b); \
      s1[_n] = fmaf(_da, s1[_n], _xd1*_b); \
      _a0 = fmaf(s0[_n], _c, _a0); \
      _a1 = fmaf(s1[_n], _c, _a1); \
      float _b2 = b2f_raw(G##B1[_i][_n]); \
      float _c2 = b2f_raw(G##C1[_i][_n]); \
      s0[8+_n] = fmaf(_da, s0[8+_n], _xd0*_b2); \
      s1[8+_n] = fmaf(_da, s1[8+_n], _xd1*_b2); \
      _a0 = fmaf(s0[8+_n], _c2, _a0); \
      _a1 = fmaf(s1[8+_n], _c2, _a1); \
    } \
    *(unsigned*)(xw + (long)((T0)+_i)*CONVD + xoff) = \
        pack_bf16x2(_a0 + Dv*_x0, _a1 + Dv*_x1); \
  } }while(0)

__global__ __launch_bounds__(256,1) void chunk_local(const bf16* __restrict__ xbc,
    const float2* __restrict__ dadt, float* __restrict__ SC, float* __restrict__ Pc)
{
  int c = blockIdx.x;
  int dbh = blockIdx.y*4 + (threadIdx.x >> 6);
  int lane = threadIdx.x & 63;
  int dir = dbh >> 5, b = (dbh >> 3) & 3, h = dbh & 7;
  const bf16* xr = xbc + ((long)dir*BT + (long)b*TT) * CONVD;
  const float2* ddr = dadt + (long)dbh*TT;
  const int xoff = h*HD + lane*2;
  float s0[16], s1[16];
  #pragma unroll
  for (int n=0;n<16;n++){ s0[n]=0.f; s1[n]=0.f; }
  float pacc = 1.f;
  const int c0 = c*CL;

  unsigned Ax[4], Bx[4]; short8 AB0[4], AB1[4], BB0[4], BB1[4]; float2 Ad[4], Bd[4];
  CLG_LOAD(A, c0);
  for (int t0 = c0; t0 < c0+CL; t0 += 8){
    CLG_LOAD(B, t0+4);
    CLG_STEP(A);
    if (t0+8 < c0+CL) CLG_LOAD(A, t0+8);
    CLG_STEP(B);
  }
  float* sc = SC + (long)c*NE + (long)dbh*2048 + lane*32;
  #pragma unroll
  for (int n=0;n<16;n++){ sc[n] = s0[n]; sc[16+n] = s1[n]; }
  if (lane == 0) Pc[dbh*NCH + c] = pacc;
}

__global__ __launch_bounds__(256) void chunk_combine(float* __restrict__ SC,
    const float* __restrict__ Pc)
{
  int e = blockIdx.x*256 + threadIdx.x;   // 131072 total
  int dbh = e >> 11;
  float s = 0.f;
  #pragma unroll
  for (int c=0;c<NCH;c++){
    float tmp = SC[(long)c*NE + e];
    SC[(long)c*NE + e] = s;               // exclusive scan in place -> S_init
    s = Pc[dbh*NCH + c]*s + tmp;
  }
}

__global__ __launch_bounds__(256,1) void chunk_apply(bf16* __restrict__ xbc,
    const float2* __restrict__ dadt, const float* __restrict__ SC,
    const bf16* __restrict__ D0, const bf16* __restrict__ D1)
{
  int c = blockIdx.x;
  int dbh = blockIdx.y*4 + (threadIdx.x >> 6);
  int lane = threadIdx.x & 63;
  int dir = dbh >> 5, b = (dbh >> 3) & 3, h = dbh & 7;
  const bf16* xr = xbc + ((long)dir*BT + (long)b*TT) * CONVD;
  bf16* xw = xbc + ((long)dir*BT + (long)b*TT) * CONVD;
  const float2* ddr = dadt + (long)dbh*TT;
  const int xoff = h*HD + lane*2;
  float Dv = __bfloat162float(dir ? D1[h] : D0[h]);
  const float* sc = SC + (long)c*NE + (long)dbh*2048 + lane*32;
  float s0[16], s1[16];
  #pragma unroll
  for (int n=0;n<16;n++){ s0[n] = sc[n]; s1[n] = sc[16+n]; }
  const int c0 = c*CL;

  unsigned Ax[4], Bx[4];
  short8 AB0[4], AB1[4], BB0[4], BB1[4], AC0[4], AC1[4], BC0[4], BC1[4];
  float2 Ad[4], Bd[4];
  CAG_LOAD(A, c0);
  for (int t0 = c0; t0 < c0+CL; t0 += 8){
    CAG_LOAD(B, t0+4);
    CAG_STEP(A, t0);
    if (t0+8 < c0+CL) CAG_LOAD(A, t0+8);
    CAG_STEP(B, t0+4);
  }
}

// ---------------------------------------------------------------------------
// g = y*silu(z), gated RMSNorm; in place into z-cols of zx. Vectorized short4.
// ---------------------------------------------------------------------------
__global__ __launch_bounds__(256) void gate_rms(const bf16* __restrict__ xbc, bf16* zx,
    const bf16* __restrict__ rw0, const bf16* __restrict__ rw1)
{
  __shared__ float sb[8];
  int bt = blockIdx.x, dir = blockIdx.y;
  const bf16* yr = xbc + ((long)dir*BT + bt)*CONVD;
  bf16* zr = zx + ((long)dir*BT + bt)*DPROJ;
  const bf16* rw = dir ? rw1 : rw0;
  int c = threadIdx.x*4;                        // 256*4 = 1024 = DI exactly
  short4v yv4 = *(const short4v*)(yr + c);
  short4v zv4 = *(const short4v*)(zr + c);
  short4v rw4 = *(const short4v*)(rw + c);
  float gv[4], ss = 0.f, dummy = 0.f;
  #pragma unroll
  for (int k=0;k<4;k++){
    float yv = b2f_raw(yv4[k]);
    float zv = b2f_raw(zv4[k]);
    float sg = 1.f/(1.f+expf(-zv));
    gv[k] = yv * zv * sg;
    ss += gv[k]*gv[k];
  }
  red2(ss, dummy, sb);
  float sc = rsqrtf(ss / DI + 1e-5f);
  short4v ov;
  #pragma unroll
  for (int k=0;k<4;k++)
    ov[k] = (short)__bfloat16_as_ushort(__float2bfloat16(gv[k]*sc*b2f_raw(rw4[k])));
  *(short4v*)(zr + c) = ov;
}

// ---------------------------------------------------------------------------
// Final LN over concat(h_f[b,t], h_b[b,T-1-t]) (1024) -> d_out
// ---------------------------------------------------------------------------
__global__ __launch_bounds__(256) void final_ln(const bf16* __restrict__ h,
    const bf16* __restrict__ lw, const bf16* __restrict__ lb, void* out,
    int mode, const int* flagp)
{
  __shared__ float sb[8];
  int bt = blockIdx.x; int b = bt >> 11, t = bt & 2047;
  int f32out = mode ? *flagp : 0;
  const bf16* rf = h + (long)bt*DM;
  const bf16* rb = h + ((long)BT + (long)b*TT + (TT-1-t))*DM;
  float v[4], s = 0.f, ss = 0.f;
  #pragma unroll
  for (int i=0;i<4;i++){
    int c = threadIdx.x + i*256;
    v[i] = __bfloat162float(c < DM ? rf[c] : rb[c-DM]);
    s += v[i]; ss += v[i]*v[i];
  }
  red2(s, ss, sb);
  float m = s / (2*DM);
  float var = ss / (2*DM) - m*m;
  float rs = rsqrtf(fmaxf(var, 0.f) + 1e-5f);
  #pragma unroll
  for (int i=0;i<4;i++){
    int c = threadIdx.x + i*256;
    float o = (v[i]-m)*rs*__bfloat162float(lw[c]) + __bfloat162float(lb[c]);
    if (f32out) ((float*)out)[(long)bt*(2*DM) + c] = o;
    else        ((bf16*)out)[(long)bt*(2*DM) + c] = __float2bfloat16(o);
  }
}

// ---------------------------------------------------------------------------
extern "C" void kernel_launch(void* const* d_in, const int* in_sizes, int n_in,
                              void* d_out, int out_size, void* d_ws, size_t ws_size,
                              hipStream_t stream)
{
  char* wsp = (char*)d_ws;
  auto take = [&](size_t bytes){ char* p = wsp; wsp += (bytes + 63) & ~(size_t)63; return p; };
  int*   flagp = (int*)  take(4);
  bf16*  h     = (bf16*) take((size_t)2*BT*DM*2);      // 16.78 MB
  bf16*  zx    = (bf16*) take((size_t)2*BT*DPROJ*2);   // 68.42 MB (z gated in place)
  bf16*  xbc   = (bf16*) take((size_t)2*BT*CONVD*2);   // 34.60 MB (y scanned in place)
  float2* dadt = (float2*)take((size_t)2*BB*NH*TT*8);  // 1.05 MB
  float* draw  = (float*)take((size_t)2*BT*NH*4);      // 0.52 MB
  float* Pc    = (float*)take((size_t)64*NCH*4);       // 4 KB
  float* SC    = (float*)take((size_t)NCH*NE*4);       // 8.39 MB chunk states
  size_t needDirect = (size_t)(wsp - (char*)d_ws);     // ~129.8 MB (proven safe r4/r5)

  static const int cnt[23] = {
    BT*256, DM*256, DM, DM, DM, 2*DM, 2*DM,
    NL*DPROJ*DM, NL*CONVD*4, NL*CONVD, NL*NH, NL*NH, NL*NH, NL*DI, NL*DM*DI,
    NL*DPROJ*DM, NL*CONVD*4, NL*CONVD, NL*NH, NL*NH, NL*NH, NL*DI, NL*DM*DI };
  bf16* canon[23];
  for (int i = 0; i < 23; ++i) canon[i] = (bf16*)take((size_t)cnt[i]*2);
  size_t needFull = (size_t)(wsp - (char*)d_ws);       // ~167.9 MB

  const int convMode = (ws_size >= needFull) ? 1 : 0;

  const bf16* in[23];
  if (convMode){
    detect_dtype<<<1,256,0,stream>>>(d_in[0], flagp);
    for (int i = 0; i < 23; ++i){
      int grid = (cnt[i] + 255)/256; if (grid > 2048) grid = 2048;
      convert_in<<<grid,256,0,stream>>>(d_in[i], canon[i], cnt[i], flagp);
      in[i] = canon[i];
    }
  } else {
    for (int i = 0; i < 23; ++i) in[i] = (const bf16*)d_in[i];
  }

  const bf16* x       = in[0];
  const bf16* embed_w = in[1];
  const bf16* embed_b = in[2];
  const bf16* ln1_w   = in[3];
  const bf16* ln1_b   = in[4];
  const bf16* lnout_w = in[5];
  const bf16* lnout_b = in[6];
  const bf16* in_w[2]   = {in[7],  in[15]};
  const bf16* conv_w[2] = {in[8],  in[16]};
  const bf16* conv_b[2] = {in[9],  in[17]};
  const bf16* dt_b[2]   = {in[10], in[18]};
  const bf16* A_log[2]  = {in[11], in[19]};
  const bf16* Dp[2]     = {in[12], in[20]};
  const bf16* rms_w[2]  = {in[13], in[21]};
  const bf16* out_w[2]  = {in[14], in[22]};

  bf16* hpre = xbc;   // embed output parks in xbc (free until layer-0 conv)

  gemm_nt<1,128><<<dim3(64,4,1),256,0,stream>>>(x, embed_w, embed_w, hpre, embed_b, nullptr,
                                            BT, DM, 256, 256, 0, 0);
  embed_ln<<<dim3(BT),256,0,stream>>>(hpre, ln1_w, ln1_b, h);

  for (int i = 0; i < NL; ++i){
    gemm_nt<3,256><<<dim3(32,17,2),256,0,stream>>>(h, in_w[0]+(size_t)i*DPROJ*DM, in_w[1]+(size_t)i*DPROJ*DM,
        zx, nullptr, draw, BT, DPROJ, DM, DM, (long)BT*DM, (long)BT*DPROJ);
    conv_silu<<<dim3(BT,2),256,0,stream>>>(zx, conv_w[0]+(size_t)i*CONVD*4, conv_w[1]+(size_t)i*CONVD*4,
        conv_b[0]+(size_t)i*CONVD, conv_b[1]+(size_t)i*CONVD, xbc);
    dt_kernel<<<dim3(512),256,0,stream>>>(draw, dt_b[0]+i*NH, dt_b[1]+i*NH,
        A_log[0]+i*NH, A_log[1]+i*NH, dadt);
    chunk_local<<<dim3(NCH,16),256,0,stream>>>(xbc, dadt, SC, Pc);
    chunk_combine<<<dim3(NE/256),256,0,stream>>>(SC, Pc);
    chunk_apply<<<dim3(NCH,16),256,0,stream>>>(xbc, dadt, SC, Dp[0]+i*NH, Dp[1]+i*NH);
    gate_rms<<<dim3(BT,2),256,0,stream>>>(xbc, zx, rms_w[0]+(size_t)i*DI, rms_w[1]+(size_t)i*DI);
    gemm_nt<2,128><<<dim3(64,4,2),256,0,stream>>>(zx, out_w[0]+(size_t)i*DM*DI, out_w[1]+(size_t)i*DM*DI,
        h, h, nullptr, BT, DM, DI, DPROJ, (long)BT*DPROJ, (long)BT*DM);
  }

  final_ln<<<dim3(BT),256,0,stream>>>(h, lnout_w, lnout_b, d_out, convMode, flagp);
  (void)needDirect; (void)in_sizes; (void)n_in; (void)out_size;
}